// Round 2
// baseline (435.708 us; speedup 1.0000x reference)
//
#include <hip/hip_runtime.h>
#include <math.h>

// GAT 2-layer forward. N=50000 nodes, E=800000 edges, D=128, H=4 heads, F=32.
constexpr int NN = 50000;
constexpr int NE = 800000;
constexpr int D  = 128;
constexpr int NH = 4;

// ---------------- CSR build (once per call; shared by both layers) ----------
__global__ void hist_kernel(const int* __restrict__ dst, int* __restrict__ cnt) {
    int e = blockIdx.x * blockDim.x + threadIdx.x;
    if (e < NE) atomicAdd(&cnt[dst[e]], 1);
}

// Single-block scan: each thread serially sums a contiguous chunk, one
// 1024-wide Hillis-Steele over thread totals, then serial writeback.
constexpr int SCAN_T = 1024;
constexpr int CHUNK = (NN + SCAN_T - 1) / SCAN_T;   // 49
__global__ __launch_bounds__(1024) void scan_kernel(const int* __restrict__ cnt,
                                                    int* __restrict__ row_ptr,
                                                    int* __restrict__ wr_ptr) {
    const int t = threadIdx.x;
    const int begin = t * CHUNK;
    const int fin = min(begin + CHUNK, NN);
    int sum = 0;
    for (int i = begin; i < fin; ++i) sum += cnt[i];
    __shared__ int s[SCAN_T];
    s[t] = sum;
    __syncthreads();
    for (int off = 1; off < SCAN_T; off <<= 1) {
        int v = (t >= off) ? s[t - off] : 0;
        __syncthreads();
        s[t] += v;
        __syncthreads();
    }
    int run = s[t] - sum;   // exclusive prefix of this thread's chunk
    for (int i = begin; i < fin; ++i) {
        int c = cnt[i];
        row_ptr[i] = run; wr_ptr[i] = run;
        run += c;
    }
    if (t == SCAN_T - 1) { row_ptr[NN] = run; wr_ptr[NN] = run; }
}

__global__ void scatter_kernel(const int* __restrict__ src, const int* __restrict__ dst,
                               int* __restrict__ wr_ptr, int* __restrict__ srcs) {
    int e = blockIdx.x * blockDim.x + threadIdx.x;
    if (e < NE) {
        int pos = atomicAdd(&wr_ptr[dst[e]], 1);
        srcs[pos] = src[e];
    }
}

// ---------------- h = x @ W, fused alpha_s/alpha_d head reductions ----------
// Block = 128 threads (thread j owns output column j), ROWS rows per block.
// a_src[l] flattens so column j's coefficient is a_src[j] -> per-head
// reduction is a width-32 shuffle reduce.
constexpr int ROWS = 16;
__global__ __launch_bounds__(128) void gemm_alpha_kernel(
    const float* __restrict__ x, const float* __restrict__ W,
    const float* __restrict__ a_src, const float* __restrict__ a_dst,
    float* __restrict__ h, float* __restrict__ alpha_s, float* __restrict__ alpha_d)
{
    __shared__ float xs[ROWS][D];
    const int j = threadIdx.x;
    const int row0 = blockIdx.x * ROWS;
    #pragma unroll
    for (int r = 0; r < ROWS; ++r) {
        int n = row0 + r;
        xs[r][j] = (n < NN) ? x[(size_t)n * D + j] : 0.f;
    }
    __syncthreads();
    float acc[ROWS];
    #pragma unroll
    for (int r = 0; r < ROWS; ++r) acc[r] = 0.f;
    for (int k = 0; k < D; ++k) {
        float w = W[k * D + j];
        #pragma unroll
        for (int r = 0; r < ROWS; ++r) acc[r] = fmaf(xs[r][k], w, acc[r]);
    }
    const float as = a_src[j], ad = a_dst[j];
    #pragma unroll
    for (int r = 0; r < ROWS; ++r) {
        int n = row0 + r;
        if (n < NN) h[(size_t)n * D + j] = acc[r];
        float vs = acc[r] * as;
        float vd = acc[r] * ad;
        #pragma unroll
        for (int off = 16; off; off >>= 1) {
            vs += __shfl_xor(vs, off, 32);
            vd += __shfl_xor(vd, off, 32);
        }
        if ((j & 31) == 0 && n < NN) {
            alpha_s[n * NH + (j >> 5)] = vs;
            alpha_d[n * NH + (j >> 5)] = vd;
        }
    }
}

// ---------------- per-dst-node gather + softmax + aggregate + epilogue ------
// One 64-lane wave per node. Each 32-lane half-wave processes one edge per
// inner iteration; lane (l32) owns 4 consecutive columns -> float4 loads of
// h rows (512 B coalesced per half-wave). Softmax normalization is hoisted
// out of the edge loop (denominator depends only on dst).
__global__ __launch_bounds__(256) void gather_kernel(
    const float* __restrict__ h, const float* __restrict__ alpha_s,
    const float* __restrict__ alpha_d, const int* __restrict__ row_ptr,
    const int* __restrict__ srcs, const float* __restrict__ x_in,
    const float* __restrict__ bias, float* __restrict__ out, int apply_act)
{
    const int wave = threadIdx.x >> 6;
    const int lane = threadIdx.x & 63;
    const int half = lane >> 5;          // which edge of the pair
    const int l32  = lane & 31;          // column group: cols [4*l32, 4*l32+4)
    const int head = l32 >> 3;           // all 4 cols share one head
    const int n = blockIdx.x * 4 + wave;
    if (n >= NN) return;

    const int start = row_ptr[n];
    const int end   = row_ptr[n + 1];
    const float4 ad4 = *(const float4*)&alpha_d[n * NH];

    float4 acc = {0.f, 0.f, 0.f, 0.f};
    float ds0 = 0.f, ds1 = 0.f, ds2 = 0.f, ds3 = 0.f;

    for (int base = start; base < end; base += 64) {
        const int cnt = min(64, end - base);
        int msrc = 0;
        float w0 = 0.f, w1 = 0.f, w2 = 0.f, w3 = 0.f;
        if (lane < cnt) {
            msrc = srcs[base + lane];
            const float4 as4 = *(const float4*)&alpha_s[msrc * NH];
            float e0 = as4.x + ad4.x; e0 = (e0 > 0.f) ? e0 : 0.2f * e0;
            float e1 = as4.y + ad4.y; e1 = (e1 > 0.f) ? e1 : 0.2f * e1;
            float e2 = as4.z + ad4.z; e2 = (e2 > 0.f) ? e2 : 0.2f * e2;
            float e3 = as4.w + ad4.w; e3 = (e3 > 0.f) ? e3 : 0.2f * e3;
            w0 = __expf(e0); w1 = __expf(e1); w2 = __expf(e2); w3 = __expf(e3);
            ds0 += w0; ds1 += w1; ds2 += w2; ds3 += w3;
        }
        for (int m = 0; m < cnt; m += 2) {
            const int me = m + half;     // lane me>=cnt has w*=0, msrc=0 -> harmless
            int s = __shfl(msrc, me);
            float b0 = __shfl(w0, me), b1 = __shfl(w1, me);
            float b2 = __shfl(w2, me), b3 = __shfl(w3, me);
            float ww = (head < 2) ? (head == 0 ? b0 : b1)
                                  : (head == 2 ? b2 : b3);
            const float4 hv = *(const float4*)(h + (size_t)s * D + l32 * 4);
            acc.x = fmaf(ww, hv.x, acc.x);
            acc.y = fmaf(ww, hv.y, acc.y);
            acc.z = fmaf(ww, hv.z, acc.z);
            acc.w = fmaf(ww, hv.w, acc.w);
        }
    }
    // combine the two half-wave accumulators
    acc.x += __shfl_xor(acc.x, 32);
    acc.y += __shfl_xor(acc.y, 32);
    acc.z += __shfl_xor(acc.z, 32);
    acc.w += __shfl_xor(acc.w, 32);
    // reduce denominators across the wave
    #pragma unroll
    for (int off = 32; off; off >>= 1) {
        ds0 += __shfl_xor(ds0, off);
        ds1 += __shfl_xor(ds1, off);
        ds2 += __shfl_xor(ds2, off);
        ds3 += __shfl_xor(ds3, off);
    }
    if (half == 0) {
        const float dh = (head == 0) ? ds0 : (head == 1) ? ds1
                       : (head == 2) ? ds2 : ds3;
        const float inv = 1.f / (dh + 1e-16f);
        const size_t off4 = (size_t)n * D + l32 * 4;
        const float4 xi = *(const float4*)(x_in + off4);
        const float4 bi = *(const float4*)(bias + l32 * 4);
        float4 o;
        o.x = acc.x * inv + xi.x + bi.x;
        o.y = acc.y * inv + xi.y + bi.y;
        o.z = acc.z * inv + xi.z + bi.z;
        o.w = acc.w * inv + xi.w + bi.w;
        if (apply_act) {
            o.x = (o.x > 0.f) ? o.x : expm1f(o.x);
            o.y = (o.y > 0.f) ? o.y : expm1f(o.y);
            o.z = (o.z > 0.f) ? o.z : expm1f(o.z);
            o.w = (o.w > 0.f) ? o.w : expm1f(o.w);
        }
        *(float4*)(out + off4) = o;
    }
}

// ---------------------------------------------------------------------------
extern "C" void kernel_launch(void* const* d_in, const int* in_sizes, int n_in,
                              void* d_out, int out_size, void* d_ws, size_t ws_size,
                              hipStream_t stream) {
    const float* x     = (const float*)d_in[0];
    const int*   ei    = (const int*)d_in[1];
    const float* W     = (const float*)d_in[2];
    const float* a_src = (const float*)d_in[3];
    const float* a_dst = (const float*)d_in[4];
    const float* bias  = (const float*)d_in[5];
    float* outp = (float*)d_out;

    const int* e_src = ei;
    const int* e_dst = ei + NE;

    // workspace layout (bytes)
    char* base = (char*)d_ws;
    float* h       = (float*)(base);                       // NN*D
    float* x1      = (float*)(base + 25600000);            // NN*D
    float* al_s    = (float*)(base + 51200000);            // NN*NH
    float* al_d    = (float*)(base + 52000000);            // NN*NH
    int*   row_ptr = (int*)  (base + 52800000);            // NN+1
    int*   wr_ptr  = (int*)  (base + 53000064);            // NN+1
    int*   cnt     = (int*)  (base + 53200128);            // NN
    int*   srcs    = (int*)  (base + 53400128);            // NE

    // ---- CSR build (once; graph shared by both layers) ----
    hipMemsetAsync(cnt, 0, NN * sizeof(int), stream);
    hist_kernel<<<(NE + 255) / 256, 256, 0, stream>>>(e_dst, cnt);
    scan_kernel<<<1, SCAN_T, 0, stream>>>(cnt, row_ptr, wr_ptr);
    scatter_kernel<<<(NE + 255) / 256, 256, 0, stream>>>(e_src, e_dst, wr_ptr, srcs);

    const int gemm_blocks   = (NN + ROWS - 1) / ROWS;
    const int gather_blocks = (NN + 3) / 4;

    // ---- layer 0 ----
    gemm_alpha_kernel<<<gemm_blocks, 128, 0, stream>>>(x, W, a_src, a_dst, h, al_s, al_d);
    gather_kernel<<<gather_blocks, 256, 0, stream>>>(h, al_s, al_d, row_ptr, srcs,
                                                     x, bias, x1, 1);
    // ---- layer 1 ----
    gemm_alpha_kernel<<<gemm_blocks, 128, 0, stream>>>(x1, W + D * D, a_src + D,
                                                       a_dst + D, h, al_s, al_d);
    gather_kernel<<<gather_blocks, 256, 0, stream>>>(h, al_s, al_d, row_ptr, srcs,
                                                     x1, bias + D, outp, 0);
}

// Round 3
// 303.742 us; speedup vs baseline: 1.4345x; 1.4345x over previous
//
#include <hip/hip_runtime.h>
#include <math.h>

// GAT 2-layer forward. N=50000 nodes, E=800000 edges, D=128, H=4 heads, F=32.
constexpr int NN = 50000;
constexpr int NE = 800000;
constexpr int D  = 128;
constexpr int NH = 4;

// ---------------- CSR build (once per call; shared by both layers) ----------
__global__ void hist_kernel(const int* __restrict__ dst, int* __restrict__ cnt) {
    int e = blockIdx.x * blockDim.x + threadIdx.x;
    if (e < NE) atomicAdd(&cnt[dst[e]], 1);
}

// Hierarchical scan: (1) per-block sums, (2) scan of 196 block sums, (3)
// per-block rescan + offset. All loads coalesced, all 256 CUs in play.
constexpr int SB = 256;
constexpr int NB = (NN + SB - 1) / SB;   // 196

__global__ __launch_bounds__(256) void scan_partial_kernel(
    const int* __restrict__ cnt, int* __restrict__ bsum)
{
    int i = blockIdx.x * SB + threadIdx.x;
    int v = (i < NN) ? cnt[i] : 0;
    #pragma unroll
    for (int off = 32; off; off >>= 1) v += __shfl_down(v, off);
    __shared__ int ws[4];
    if ((threadIdx.x & 63) == 0) ws[threadIdx.x >> 6] = v;
    __syncthreads();
    if (threadIdx.x == 0) bsum[blockIdx.x] = ws[0] + ws[1] + ws[2] + ws[3];
}

__global__ __launch_bounds__(256) void scan_bsum_kernel(
    const int* __restrict__ bsum, int* __restrict__ bpre,
    int* __restrict__ row_ptr, int* __restrict__ wr_ptr)
{
    const int t = threadIdx.x;
    int v = (t < NB) ? bsum[t] : 0;
    __shared__ int s[256];
    s[t] = v;
    __syncthreads();
    for (int off = 1; off < 256; off <<= 1) {
        int u = (t >= off) ? s[t - off] : 0;
        __syncthreads();
        s[t] += u;
        __syncthreads();
    }
    if (t < NB) bpre[t] = s[t] - v;
    if (t == 255) { row_ptr[NN] = s[255]; wr_ptr[NN] = s[255]; }
}

__global__ __launch_bounds__(256) void scan_final_kernel(
    const int* __restrict__ cnt, const int* __restrict__ bpre,
    int* __restrict__ row_ptr, int* __restrict__ wr_ptr)
{
    const int t = threadIdx.x;
    const int i = blockIdx.x * SB + t;
    int v = (i < NN) ? cnt[i] : 0;
    __shared__ int s[256];
    s[t] = v;
    __syncthreads();
    for (int off = 1; off < 256; off <<= 1) {
        int u = (t >= off) ? s[t - off] : 0;
        __syncthreads();
        s[t] += u;
        __syncthreads();
    }
    int excl = s[t] - v + bpre[blockIdx.x];
    if (i < NN) { row_ptr[i] = excl; wr_ptr[i] = excl; }
}

__global__ void scatter_kernel(const int* __restrict__ src, const int* __restrict__ dst,
                               int* __restrict__ wr_ptr, int* __restrict__ srcs) {
    int e = blockIdx.x * blockDim.x + threadIdx.x;
    if (e < NE) {
        int pos = atomicAdd(&wr_ptr[dst[e]], 1);
        srcs[pos] = src[e];
    }
}

// ---------------- h = x @ W, fused alpha_s/alpha_d head reductions ----------
// h is stored as bf16 (RNE): halves the gather kernel's dominant byte stream.
// Alphas are computed from the f32 accumulator (full precision).
constexpr int ROWS = 16;
__global__ __launch_bounds__(128) void gemm_alpha_kernel(
    const float* __restrict__ x, const float* __restrict__ W,
    const float* __restrict__ a_src, const float* __restrict__ a_dst,
    unsigned short* __restrict__ hb, float* __restrict__ alpha_s,
    float* __restrict__ alpha_d)
{
    __shared__ float xs[ROWS][D];
    const int j = threadIdx.x;
    const int row0 = blockIdx.x * ROWS;
    #pragma unroll
    for (int r = 0; r < ROWS; ++r) {
        int n = row0 + r;
        xs[r][j] = (n < NN) ? x[(size_t)n * D + j] : 0.f;
    }
    __syncthreads();
    float acc[ROWS];
    #pragma unroll
    for (int r = 0; r < ROWS; ++r) acc[r] = 0.f;
    for (int k = 0; k < D; ++k) {
        float w = W[k * D + j];
        #pragma unroll
        for (int r = 0; r < ROWS; ++r) acc[r] = fmaf(xs[r][k], w, acc[r]);
    }
    const float as = a_src[j], ad = a_dst[j];
    #pragma unroll
    for (int r = 0; r < ROWS; ++r) {
        int n = row0 + r;
        if (n < NN) {
            unsigned bits = __float_as_uint(acc[r]);
            unsigned r16 = (bits + 0x7FFFu + ((bits >> 16) & 1u)) >> 16;  // RNE
            hb[(size_t)n * D + j] = (unsigned short)r16;
        }
        float vs = acc[r] * as;
        float vd = acc[r] * ad;
        #pragma unroll
        for (int off = 16; off; off >>= 1) {
            vs += __shfl_xor(vs, off, 32);
            vd += __shfl_xor(vd, off, 32);
        }
        if ((j & 31) == 0 && n < NN) {
            alpha_s[n * NH + (j >> 5)] = vs;
            alpha_d[n * NH + (j >> 5)] = vd;
        }
    }
}

// ---------------- per-dst-node gather + softmax + aggregate + epilogue ------
// One 64-lane wave per node; each 32-lane half-wave handles one edge per
// inner step; lane owns 4 consecutive columns (ushort4 = 8B bf16 load).
// Softmax normalization hoisted out of the edge loop.
__global__ __launch_bounds__(256) void gather_kernel(
    const unsigned short* __restrict__ hb, const float* __restrict__ alpha_s,
    const float* __restrict__ alpha_d, const int* __restrict__ row_ptr,
    const int* __restrict__ srcs, const float* __restrict__ x_in,
    const float* __restrict__ bias, float* __restrict__ out, int apply_act)
{
    const int wave = threadIdx.x >> 6;
    const int lane = threadIdx.x & 63;
    const int half = lane >> 5;          // which edge of the pair
    const int l32  = lane & 31;          // column group: cols [4*l32, 4*l32+4)
    const int head = l32 >> 3;           // all 4 cols share one head
    const int n = blockIdx.x * 4 + wave;
    if (n >= NN) return;

    const int start = row_ptr[n];
    const int end   = row_ptr[n + 1];
    const float4 ad4 = *(const float4*)&alpha_d[n * NH];

    float4 acc = {0.f, 0.f, 0.f, 0.f};
    float ds0 = 0.f, ds1 = 0.f, ds2 = 0.f, ds3 = 0.f;

    for (int base = start; base < end; base += 64) {
        const int cnt = min(64, end - base);
        int msrc = 0;
        float w0 = 0.f, w1 = 0.f, w2 = 0.f, w3 = 0.f;
        if (lane < cnt) {
            msrc = srcs[base + lane];
            const float4 as4 = *(const float4*)&alpha_s[msrc * NH];
            float e0 = as4.x + ad4.x; e0 = (e0 > 0.f) ? e0 : 0.2f * e0;
            float e1 = as4.y + ad4.y; e1 = (e1 > 0.f) ? e1 : 0.2f * e1;
            float e2 = as4.z + ad4.z; e2 = (e2 > 0.f) ? e2 : 0.2f * e2;
            float e3 = as4.w + ad4.w; e3 = (e3 > 0.f) ? e3 : 0.2f * e3;
            w0 = __expf(e0); w1 = __expf(e1); w2 = __expf(e2); w3 = __expf(e3);
            ds0 += w0; ds1 += w1; ds2 += w2; ds3 += w3;
        }
        for (int m = 0; m < cnt; m += 2) {
            const int me = m + half;     // me>=cnt lanes have w*=0, msrc=0 -> 0 contrib
            int s = __shfl(msrc, me);
            float b0 = __shfl(w0, me), b1 = __shfl(w1, me);
            float b2 = __shfl(w2, me), b3 = __shfl(w3, me);
            float ww = (head < 2) ? (head == 0 ? b0 : b1)
                                  : (head == 2 ? b2 : b3);
            const ushort4 hv = *(const ushort4*)(hb + (size_t)s * D + l32 * 4);
            acc.x = fmaf(ww, __uint_as_float((unsigned)hv.x << 16), acc.x);
            acc.y = fmaf(ww, __uint_as_float((unsigned)hv.y << 16), acc.y);
            acc.z = fmaf(ww, __uint_as_float((unsigned)hv.z << 16), acc.z);
            acc.w = fmaf(ww, __uint_as_float((unsigned)hv.w << 16), acc.w);
        }
    }
    // combine the two half-wave accumulators
    acc.x += __shfl_xor(acc.x, 32);
    acc.y += __shfl_xor(acc.y, 32);
    acc.z += __shfl_xor(acc.z, 32);
    acc.w += __shfl_xor(acc.w, 32);
    // reduce denominators across the wave
    #pragma unroll
    for (int off = 32; off; off >>= 1) {
        ds0 += __shfl_xor(ds0, off);
        ds1 += __shfl_xor(ds1, off);
        ds2 += __shfl_xor(ds2, off);
        ds3 += __shfl_xor(ds3, off);
    }
    if (half == 0) {
        const float dh = (head == 0) ? ds0 : (head == 1) ? ds1
                       : (head == 2) ? ds2 : ds3;
        const float inv = 1.f / (dh + 1e-16f);
        const size_t off4 = (size_t)n * D + l32 * 4;
        const float4 xi = *(const float4*)(x_in + off4);
        const float4 bi = *(const float4*)(bias + l32 * 4);
        float4 o;
        o.x = acc.x * inv + xi.x + bi.x;
        o.y = acc.y * inv + xi.y + bi.y;
        o.z = acc.z * inv + xi.z + bi.z;
        o.w = acc.w * inv + xi.w + bi.w;
        if (apply_act) {
            o.x = (o.x > 0.f) ? o.x : expm1f(o.x);
            o.y = (o.y > 0.f) ? o.y : expm1f(o.y);
            o.z = (o.z > 0.f) ? o.z : expm1f(o.z);
            o.w = (o.w > 0.f) ? o.w : expm1f(o.w);
        }
        *(float4*)(out + off4) = o;
    }
}

// ---------------------------------------------------------------------------
extern "C" void kernel_launch(void* const* d_in, const int* in_sizes, int n_in,
                              void* d_out, int out_size, void* d_ws, size_t ws_size,
                              hipStream_t stream) {
    const float* x     = (const float*)d_in[0];
    const int*   ei    = (const int*)d_in[1];
    const float* W     = (const float*)d_in[2];
    const float* a_src = (const float*)d_in[3];
    const float* a_dst = (const float*)d_in[4];
    const float* bias  = (const float*)d_in[5];
    float* outp = (float*)d_out;

    const int* e_src = ei;
    const int* e_dst = ei + NE;

    // workspace layout (bytes)
    char* base = (char*)d_ws;
    unsigned short* hb = (unsigned short*)(base);          // NN*D bf16 (12.8MB)
    float* x1      = (float*)(base + 25600000);            // NN*D f32
    float* al_s    = (float*)(base + 51200000);            // NN*NH
    float* al_d    = (float*)(base + 52000000);            // NN*NH
    int*   row_ptr = (int*)  (base + 52800000);            // NN+1
    int*   wr_ptr  = (int*)  (base + 53000064);            // NN+1
    int*   cnt     = (int*)  (base + 53200128);            // NN
    int*   srcs    = (int*)  (base + 53400128);            // NE
    int*   bsum    = (int*)  (base + 56600128);            // NB
    int*   bpre    = (int*)  (base + 56601152);            // NB

    // ---- CSR build (once; graph shared by both layers) ----
    hipMemsetAsync(cnt, 0, NN * sizeof(int), stream);
    hist_kernel<<<(NE + 255) / 256, 256, 0, stream>>>(e_dst, cnt);
    scan_partial_kernel<<<NB, SB, 0, stream>>>(cnt, bsum);
    scan_bsum_kernel<<<1, 256, 0, stream>>>(bsum, bpre, row_ptr, wr_ptr);
    scan_final_kernel<<<NB, SB, 0, stream>>>(cnt, bpre, row_ptr, wr_ptr);
    scatter_kernel<<<(NE + 255) / 256, 256, 0, stream>>>(e_src, e_dst, wr_ptr, srcs);

    const int gemm_blocks   = (NN + ROWS - 1) / ROWS;
    const int gather_blocks = (NN + 3) / 4;

    // ---- layer 0 ----
    gemm_alpha_kernel<<<gemm_blocks, 128, 0, stream>>>(x, W, a_src, a_dst, hb, al_s, al_d);
    gather_kernel<<<gather_blocks, 256, 0, stream>>>(hb, al_s, al_d, row_ptr, srcs,
                                                     x, bias, x1, 1);
    // ---- layer 1 ----
    gemm_alpha_kernel<<<gemm_blocks, 128, 0, stream>>>(x1, W + D * D, a_src + D,
                                                       a_dst + D, hb, al_s, al_d);
    gather_kernel<<<gather_blocks, 256, 0, stream>>>(hb, al_s, al_d, row_ptr, srcs,
                                                     x1, bias + D, outp, 0);
}

// Round 4
// 239.697 us; speedup vs baseline: 1.8177x; 1.2672x over previous
//
#include <hip/hip_runtime.h>
#include <math.h>

// GAT 2-layer forward. N=50000 nodes, E=800000 edges, D=128, H=4 heads, F=32.
constexpr int NN = 50000;
constexpr int NE = 800000;
constexpr int D  = 128;
constexpr int NH = 4;

typedef __attribute__((ext_vector_type(8))) short short8v;  // 8 bf16 (4 VGPR)
typedef __attribute__((ext_vector_type(4))) float f32x4;    // MFMA accumulator

__device__ inline unsigned short rne_bf16(float f) {
    unsigned bits = __float_as_uint(f);
    return (unsigned short)((bits + 0x7FFFu + ((bits >> 16) & 1u)) >> 16);
}

// ---------------- CSR build (once per call; shared by both layers) ----------
__global__ void hist_kernel(const int* __restrict__ dst, int* __restrict__ cnt) {
    int e = blockIdx.x * blockDim.x + threadIdx.x;
    if (e < NE) atomicAdd(&cnt[dst[e]], 1);
}

constexpr int SB = 256;
constexpr int NB = (NN + SB - 1) / SB;   // 196

__global__ __launch_bounds__(256) void scan_partial_kernel(
    const int* __restrict__ cnt, int* __restrict__ bsum)
{
    int i = blockIdx.x * SB + threadIdx.x;
    int v = (i < NN) ? cnt[i] : 0;
    #pragma unroll
    for (int off = 32; off; off >>= 1) v += __shfl_down(v, off);
    __shared__ int ws[4];
    if ((threadIdx.x & 63) == 0) ws[threadIdx.x >> 6] = v;
    __syncthreads();
    if (threadIdx.x == 0) bsum[blockIdx.x] = ws[0] + ws[1] + ws[2] + ws[3];
}

__global__ __launch_bounds__(256) void scan_bsum_kernel(
    const int* __restrict__ bsum, int* __restrict__ bpre,
    int* __restrict__ row_ptr, int* __restrict__ wr_ptr)
{
    const int t = threadIdx.x;
    int v = (t < NB) ? bsum[t] : 0;
    __shared__ int s[256];
    s[t] = v;
    __syncthreads();
    for (int off = 1; off < 256; off <<= 1) {
        int u = (t >= off) ? s[t - off] : 0;
        __syncthreads();
        s[t] += u;
        __syncthreads();
    }
    if (t < NB) bpre[t] = s[t] - v;
    if (t == 255) { row_ptr[NN] = s[255]; wr_ptr[NN] = s[255]; }
}

__global__ __launch_bounds__(256) void scan_final_kernel(
    const int* __restrict__ cnt, const int* __restrict__ bpre,
    int* __restrict__ row_ptr, int* __restrict__ wr_ptr)
{
    const int t = threadIdx.x;
    const int i = blockIdx.x * SB + t;
    int v = (i < NN) ? cnt[i] : 0;
    __shared__ int s[256];
    s[t] = v;
    __syncthreads();
    for (int off = 1; off < 256; off <<= 1) {
        int u = (t >= off) ? s[t - off] : 0;
        __syncthreads();
        s[t] += u;
        __syncthreads();
    }
    int excl = s[t] - v + bpre[blockIdx.x];
    if (i < NN) { row_ptr[i] = excl; wr_ptr[i] = excl; }
}

__global__ void scatter_kernel(const int* __restrict__ src, const int* __restrict__ dst,
                               int* __restrict__ wr_ptr, int* __restrict__ srcs) {
    int e = blockIdx.x * blockDim.x + threadIdx.x;
    if (e < NE) {
        int pos = atomicAdd(&wr_ptr[dst[e]], 1);
        srcs[pos] = src[e];
    }
}

// ---------------- W repack: per-MFMA-fragment bf16 layout ------------------
// Wpk[layer][tile(8)][kstep(4)][lane(64)][j(8)] : b_frag for B[k][col] with
// col = tile*16 + (lane&15), k = kstep*32 + (lane>>4)*8 + j.
__global__ __launch_bounds__(256) void repack_kernel(const float* __restrict__ W,
                                                     unsigned short* __restrict__ Wpk) {
    int tid = blockIdx.x * 256 + threadIdx.x;   // 2 layers * 2048 frags
    if (tid >= 2 * 2048) return;
    int layer = tid >> 11;
    int rest  = tid & 2047;
    int tile  = rest >> 8;
    int kstep = (rest >> 6) & 3;
    int lane  = rest & 63;
    int col   = tile * 16 + (lane & 15);
    int kbase = kstep * 32 + (lane >> 4) * 8;
    const float* Wl = W + (size_t)layer * D * D;
    unsigned short v[8];
    #pragma unroll
    for (int j = 0; j < 8; ++j) v[j] = rne_bf16(Wl[(kbase + j) * D + col]);
    *(uint4*)(Wpk + (size_t)tid * 8) = *(const uint4*)v;
}

// ---------------- h = x @ W via MFMA; alphas from f32 accumulator ----------
// Block 256 = 4 waves; 64x128 output tile; x tile staged bf16 in swizzled LDS.
__global__ __launch_bounds__(256) void gemm_alpha_kernel(
    const float* __restrict__ x, const unsigned short* __restrict__ Wpk,
    const float* __restrict__ a_src, const float* __restrict__ a_dst,
    unsigned short* __restrict__ hb, float* __restrict__ alpha_s,
    float* __restrict__ alpha_d)
{
    __shared__ unsigned short xl[64 * 128];   // 16 KB, bf16, XOR-swizzled rows
    const int t = threadIdx.x;
    const int row0 = blockIdx.x * 64;

    // stage: 64 rows x 128 cols f32 -> bf16 LDS (8B per thread per iter)
    #pragma unroll
    for (int it = 0; it < 8; ++it) {
        int idx = it * 256 + t;
        int r   = idx >> 5;
        int c4  = (idx & 31) * 4;
        int n   = row0 + r;
        float4 v;
        if (n < NN) v = *(const float4*)(x + (size_t)n * D + c4);
        else { v.x = 0.f; v.y = 0.f; v.z = 0.f; v.w = 0.f; }
        unsigned p0 = ((unsigned)rne_bf16(v.y) << 16) | rne_bf16(v.x);
        unsigned p1 = ((unsigned)rne_bf16(v.w) << 16) | rne_bf16(v.z);
        uint2 pv; pv.x = p0; pv.y = p1;
        *(uint2*)(xl + r * 128 + (c4 ^ ((r & 7) << 3))) = pv;
    }
    __syncthreads();

    const int wv  = t >> 6;
    const int l   = t & 63;
    const int l15 = l & 15;
    const int g   = l >> 4;
    const int strip = wv * 16;
    const int arow  = strip + l15;

    f32x4 acc[8];
    #pragma unroll
    for (int i = 0; i < 8; ++i) acc[i] = (f32x4){0.f, 0.f, 0.f, 0.f};

    #pragma unroll
    for (int ks = 0; ks < 4; ++ks) {
        const int k0 = ks * 32 + g * 8;
        short8v a = *(const short8v*)(xl + arow * 128 + (k0 ^ ((arow & 7) << 3)));
        #pragma unroll
        for (int tl = 0; tl < 8; ++tl) {
            short8v b = *(const short8v*)(Wpk + ((size_t)(tl * 4 + ks) * 64 + l) * 8);
            acc[tl] = __builtin_amdgcn_mfma_f32_16x16x32_bf16(a, b, acc[tl], 0, 0, 0);
        }
    }

    // per-tile attention coefficients (col = tl*16 + l15)
    float as_t[8], ad_t[8];
    #pragma unroll
    for (int tl = 0; tl < 8; ++tl) {
        as_t[tl] = a_src[tl * 16 + l15];
        ad_t[tl] = a_dst[tl * 16 + l15];
    }

    // D layout: row = g*4 + r (within strip), col = tl*16 + l15
    #pragma unroll
    for (int r = 0; r < 4; ++r) {
        const int n = row0 + strip + g * 4 + r;
        if (n < NN) {
            #pragma unroll
            for (int tl = 0; tl < 8; ++tl)
                hb[(size_t)n * D + tl * 16 + l15] = rne_bf16(acc[tl][r]);
        }
        #pragma unroll
        for (int hd = 0; hd < NH; ++hd) {
            float ps = acc[2*hd][r] * as_t[2*hd] + acc[2*hd+1][r] * as_t[2*hd+1];
            float pd = acc[2*hd][r] * ad_t[2*hd] + acc[2*hd+1][r] * ad_t[2*hd+1];
            #pragma unroll
            for (int off = 1; off < 16; off <<= 1) {
                ps += __shfl_xor(ps, off);
                pd += __shfl_xor(pd, off);
            }
            if (l15 == 0 && n < NN) {
                alpha_s[n * NH + hd] = ps;
                alpha_d[n * NH + hd] = pd;
            }
        }
    }
}

// ---------------- per-dst-node gather + softmax + aggregate + epilogue ------
__global__ __launch_bounds__(256) void gather_kernel(
    const unsigned short* __restrict__ hb, const float* __restrict__ alpha_s,
    const float* __restrict__ alpha_d, const int* __restrict__ row_ptr,
    const int* __restrict__ srcs, const float* __restrict__ x_in,
    const float* __restrict__ bias, float* __restrict__ out, int apply_act)
{
    const int wave = threadIdx.x >> 6;
    const int lane = threadIdx.x & 63;
    const int half = lane >> 5;
    const int l32  = lane & 31;
    const int head = l32 >> 3;
    const int n = blockIdx.x * 4 + wave;
    if (n >= NN) return;

    const int start = row_ptr[n];
    const int end   = row_ptr[n + 1];
    const float4 ad4 = *(const float4*)&alpha_d[n * NH];

    float4 acc = {0.f, 0.f, 0.f, 0.f};
    float ds0 = 0.f, ds1 = 0.f, ds2 = 0.f, ds3 = 0.f;

    for (int base = start; base < end; base += 64) {
        const int cnt = min(64, end - base);
        int msrc = 0;
        float w0 = 0.f, w1 = 0.f, w2 = 0.f, w3 = 0.f;
        if (lane < cnt) {
            msrc = srcs[base + lane];
            const float4 as4 = *(const float4*)&alpha_s[msrc * NH];
            float e0 = as4.x + ad4.x; e0 = (e0 > 0.f) ? e0 : 0.2f * e0;
            float e1 = as4.y + ad4.y; e1 = (e1 > 0.f) ? e1 : 0.2f * e1;
            float e2 = as4.z + ad4.z; e2 = (e2 > 0.f) ? e2 : 0.2f * e2;
            float e3 = as4.w + ad4.w; e3 = (e3 > 0.f) ? e3 : 0.2f * e3;
            w0 = __expf(e0); w1 = __expf(e1); w2 = __expf(e2); w3 = __expf(e3);
            ds0 += w0; ds1 += w1; ds2 += w2; ds3 += w3;
        }
        for (int m = 0; m < cnt; m += 2) {
            const int me = m + half;
            int s = __shfl(msrc, me);
            float b0 = __shfl(w0, me), b1 = __shfl(w1, me);
            float b2 = __shfl(w2, me), b3 = __shfl(w3, me);
            float ww = (head < 2) ? (head == 0 ? b0 : b1)
                                  : (head == 2 ? b2 : b3);
            const ushort4 hv = *(const ushort4*)(hb + (size_t)s * D + l32 * 4);
            acc.x = fmaf(ww, __uint_as_float((unsigned)hv.x << 16), acc.x);
            acc.y = fmaf(ww, __uint_as_float((unsigned)hv.y << 16), acc.y);
            acc.z = fmaf(ww, __uint_as_float((unsigned)hv.z << 16), acc.z);
            acc.w = fmaf(ww, __uint_as_float((unsigned)hv.w << 16), acc.w);
        }
    }
    acc.x += __shfl_xor(acc.x, 32);
    acc.y += __shfl_xor(acc.y, 32);
    acc.z += __shfl_xor(acc.z, 32);
    acc.w += __shfl_xor(acc.w, 32);
    #pragma unroll
    for (int off = 32; off; off >>= 1) {
        ds0 += __shfl_xor(ds0, off);
        ds1 += __shfl_xor(ds1, off);
        ds2 += __shfl_xor(ds2, off);
        ds3 += __shfl_xor(ds3, off);
    }
    if (half == 0) {
        const float dh = (head == 0) ? ds0 : (head == 1) ? ds1
                       : (head == 2) ? ds2 : ds3;
        const float inv = 1.f / (dh + 1e-16f);
        const size_t off4 = (size_t)n * D + l32 * 4;
        const float4 xi = *(const float4*)(x_in + off4);
        const float4 bi = *(const float4*)(bias + l32 * 4);
        float4 o;
        o.x = acc.x * inv + xi.x + bi.x;
        o.y = acc.y * inv + xi.y + bi.y;
        o.z = acc.z * inv + xi.z + bi.z;
        o.w = acc.w * inv + xi.w + bi.w;
        if (apply_act) {
            o.x = (o.x > 0.f) ? o.x : expm1f(o.x);
            o.y = (o.y > 0.f) ? o.y : expm1f(o.y);
            o.z = (o.z > 0.f) ? o.z : expm1f(o.z);
            o.w = (o.w > 0.f) ? o.w : expm1f(o.w);
        }
        *(float4*)(out + off4) = o;
    }
}

// ---------------------------------------------------------------------------
extern "C" void kernel_launch(void* const* d_in, const int* in_sizes, int n_in,
                              void* d_out, int out_size, void* d_ws, size_t ws_size,
                              hipStream_t stream) {
    const float* x     = (const float*)d_in[0];
    const int*   ei    = (const int*)d_in[1];
    const float* W     = (const float*)d_in[2];
    const float* a_src = (const float*)d_in[3];
    const float* a_dst = (const float*)d_in[4];
    const float* bias  = (const float*)d_in[5];
    float* outp = (float*)d_out;

    const int* e_src = ei;
    const int* e_dst = ei + NE;

    // workspace layout (bytes)
    char* base = (char*)d_ws;
    unsigned short* hb = (unsigned short*)(base);          // NN*D bf16 (12.8MB)
    float* x1      = (float*)(base + 25600000);            // NN*D f32
    float* al_s    = (float*)(base + 51200000);            // NN*NH
    float* al_d    = (float*)(base + 52000000);            // NN*NH
    int*   row_ptr = (int*)  (base + 52800000);            // NN+1
    int*   wr_ptr  = (int*)  (base + 53000064);            // NN+1
    int*   cnt     = (int*)  (base + 53200128);            // NN
    int*   srcs    = (int*)  (base + 53400128);            // NE
    int*   bsum    = (int*)  (base + 56600128);            // NB
    int*   bpre    = (int*)  (base + 56601152);            // NB
    unsigned short* Wpk = (unsigned short*)(base + 56602176); // 2*2048*8 bf16 (64KB)

    // ---- W repack + CSR build (graph shared by both layers) ----
    repack_kernel<<<16, 256, 0, stream>>>(W, Wpk);
    hipMemsetAsync(cnt, 0, NN * sizeof(int), stream);
    hist_kernel<<<(NE + 255) / 256, 256, 0, stream>>>(e_dst, cnt);
    scan_partial_kernel<<<NB, SB, 0, stream>>>(cnt, bsum);
    scan_bsum_kernel<<<1, 256, 0, stream>>>(bsum, bpre, row_ptr, wr_ptr);
    scan_final_kernel<<<NB, SB, 0, stream>>>(cnt, bpre, row_ptr, wr_ptr);
    scatter_kernel<<<(NE + 255) / 256, 256, 0, stream>>>(e_src, e_dst, wr_ptr, srcs);

    const int gemm_blocks   = (NN + 63) / 64;
    const int gather_blocks = (NN + 3) / 4;

    // ---- layer 0 ----
    gemm_alpha_kernel<<<gemm_blocks, 256, 0, stream>>>(x, Wpk, a_src, a_dst,
                                                       hb, al_s, al_d);
    gather_kernel<<<gather_blocks, 256, 0, stream>>>(hb, al_s, al_d, row_ptr, srcs,
                                                     x, bias, x1, 1);
    // ---- layer 1 ----
    gemm_alpha_kernel<<<gemm_blocks, 256, 0, stream>>>(x1, Wpk + 2048 * 8,
                                                       a_src + D, a_dst + D,
                                                       hb, al_s, al_d);
    gather_kernel<<<gather_blocks, 256, 0, stream>>>(hb, al_s, al_d, row_ptr, srcs,
                                                     x1, bias + D, outp, 0);
}

// Round 5
// 178.263 us; speedup vs baseline: 2.4442x; 1.3446x over previous
//
#include <hip/hip_runtime.h>
#include <math.h>

// GAT 2-layer forward. N=50000 nodes, E=800000 edges, D=128, H=4 heads, F=32.
constexpr int NN = 50000;
constexpr int NE = 800000;
constexpr int D  = 128;
constexpr int NH = 4;
constexpr int NBUK = (NN + 255) / 256;   // 196 dst-range buckets of 256 nodes
constexpr int CAP  = 4608;               // max edges/bucket (mean 4096, sigma 64)

typedef __attribute__((ext_vector_type(8))) short short8v;  // 8 bf16 (4 VGPR)
typedef __attribute__((ext_vector_type(4))) float f32x4;    // MFMA accumulator

__device__ inline unsigned short rne_bf16(float f) {
    unsigned bits = __float_as_uint(f);
    return (unsigned short)((bits + 0x7FFFu + ((bits >> 16) & 1u)) >> 16);
}

// ============== CSR build: two-level bucket sort (once per call) ============
// A0: global 196-bin histogram of dst>>8, LDS-aggregated.
__global__ __launch_bounds__(256) void bucket_hist_kernel(
    const int* __restrict__ dst, int* __restrict__ btot)
{
    __shared__ int c[NBUK];
    for (int i = threadIdx.x; i < NBUK; i += 256) c[i] = 0;
    __syncthreads();
    const int base = blockIdx.x * 2048;
    #pragma unroll
    for (int i = 0; i < 8; ++i) {
        int e = base + i * 256 + threadIdx.x;
        if (e < NE) atomicAdd(&c[dst[e] >> 8], 1);
    }
    __syncthreads();
    for (int i = threadIdx.x; i < NBUK; i += 256)
        if (c[i]) atomicAdd(&btot[i], c[i]);
}

// scan of 196 bucket totals -> bucket bases + write pointers.
__global__ __launch_bounds__(256) void bucket_scan_kernel(
    const int* __restrict__ btot, int* __restrict__ bbase,
    int* __restrict__ bwp, int* __restrict__ row_ptr)
{
    const int t = threadIdx.x;
    int v = (t < NBUK) ? btot[t] : 0;
    __shared__ int s[256];
    s[t] = v;
    __syncthreads();
    for (int off = 1; off < 256; off <<= 1) {
        int u = (t >= off) ? s[t - off] : 0;
        __syncthreads();
        s[t] += u;
        __syncthreads();
    }
    if (t < NBUK) { int ex = s[t] - v; bbase[t] = ex; bwp[t] = ex; }
    if (t == 0) row_ptr[NN] = NE;
}

// A1: partition edges into buckets. One uint per edge: src(16b) | dstlo8<<16.
// Per-block LDS counting + one atomic per (block,bucket) -> grouped writes.
__global__ __launch_bounds__(256) void partition_kernel(
    const int* __restrict__ src, const int* __restrict__ dst,
    int* __restrict__ bwp, unsigned* __restrict__ bukbuf)
{
    __shared__ int cnt[NBUK];
    __shared__ int run[NBUK];
    for (int i = threadIdx.x; i < NBUK; i += 256) cnt[i] = 0;
    __syncthreads();
    const int base = blockIdx.x * 2048;
    int s_[8], b_[8], dl_[8];
    #pragma unroll
    for (int i = 0; i < 8; ++i) {
        int e = base + i * 256 + threadIdx.x;
        bool ok = (e < NE);
        s_[i] = ok ? src[e] : 0;
        int d = ok ? dst[e] : 0;
        b_[i] = d >> 8; dl_[i] = d & 255;
        if (ok) atomicAdd(&cnt[b_[i]], 1);
    }
    __syncthreads();
    for (int i = threadIdx.x; i < NBUK; i += 256)
        run[i] = cnt[i] ? atomicAdd(&bwp[i], cnt[i]) : 0;
    __syncthreads();
    #pragma unroll
    for (int i = 0; i < 8; ++i) {
        int e = base + i * 256 + threadIdx.x;
        if (e < NE) {
            int pos = atomicAdd(&run[b_[i]], 1);
            bukbuf[pos] = (unsigned)s_[i] | ((unsigned)dl_[i] << 16);
        }
    }
}

// B: per-bucket LDS counting sort -> row_ptr + coalesced ushort srcs.
__global__ __launch_bounds__(256) void bucket_sort_kernel(
    const unsigned* __restrict__ bukbuf, const int* __restrict__ btot,
    const int* __restrict__ bbase, int* __restrict__ row_ptr,
    unsigned short* __restrict__ srcs)
{
    const int b = blockIdx.x;
    const int t = threadIdx.x;
    const int cnt = min(btot[b], CAP);   // CAP guard (never triggers)
    const int base = bbase[b];
    __shared__ int hist[256];
    __shared__ int run[256];
    __shared__ int s[256];
    __shared__ unsigned short stage[CAP];
    hist[t] = 0;
    __syncthreads();
    for (int i = t; i < cnt; i += 256)
        atomicAdd(&hist[bukbuf[base + i] >> 16], 1);
    __syncthreads();
    int v = hist[t];
    s[t] = v;
    __syncthreads();
    for (int off = 1; off < 256; off <<= 1) {
        int u = (t >= off) ? s[t - off] : 0;
        __syncthreads();
        s[t] += u;
        __syncthreads();
    }
    const int excl = s[t] - v;
    const int node = b * 256 + t;
    if (node < NN) row_ptr[node] = base + excl;
    run[t] = excl;
    __syncthreads();
    for (int i = t; i < cnt; i += 256) {
        unsigned p = bukbuf[base + i];
        int pos = atomicAdd(&run[p >> 16], 1);
        stage[pos] = (unsigned short)(p & 0xFFFFu);
    }
    __syncthreads();
    for (int i = t; i < cnt; i += 256) srcs[base + i] = stage[i];
}

// ---------------- W repack: per-MFMA-fragment bf16 layout ------------------
__global__ __launch_bounds__(256) void repack_kernel(const float* __restrict__ W,
                                                     unsigned short* __restrict__ Wpk) {
    int tid = blockIdx.x * 256 + threadIdx.x;   // 2 layers * 2048 frags
    if (tid >= 2 * 2048) return;
    int layer = tid >> 11;
    int rest  = tid & 2047;
    int tile  = rest >> 8;
    int kstep = (rest >> 6) & 3;
    int lane  = rest & 63;
    int col   = tile * 16 + (lane & 15);
    int kbase = kstep * 32 + (lane >> 4) * 8;
    const float* Wl = W + (size_t)layer * D * D;
    unsigned short v[8];
    #pragma unroll
    for (int j = 0; j < 8; ++j) v[j] = rne_bf16(Wl[(kbase + j) * D + col]);
    *(uint4*)(Wpk + (size_t)tid * 8) = *(const uint4*)v;
}

// ---------------- h = x @ W via MFMA; alphas from f32 accumulator ----------
__global__ __launch_bounds__(256) void gemm_alpha_kernel(
    const float* __restrict__ x, const unsigned short* __restrict__ Wpk,
    const float* __restrict__ a_src, const float* __restrict__ a_dst,
    unsigned short* __restrict__ hb, float* __restrict__ alpha_s,
    float* __restrict__ alpha_d)
{
    __shared__ unsigned short xl[64 * 128];   // 16 KB, bf16, XOR-swizzled rows
    const int t = threadIdx.x;
    const int row0 = blockIdx.x * 64;

    #pragma unroll
    for (int it = 0; it < 8; ++it) {
        int idx = it * 256 + t;
        int r   = idx >> 5;
        int c4  = (idx & 31) * 4;
        int n   = row0 + r;
        float4 v;
        if (n < NN) v = *(const float4*)(x + (size_t)n * D + c4);
        else { v.x = 0.f; v.y = 0.f; v.z = 0.f; v.w = 0.f; }
        unsigned p0 = ((unsigned)rne_bf16(v.y) << 16) | rne_bf16(v.x);
        unsigned p1 = ((unsigned)rne_bf16(v.w) << 16) | rne_bf16(v.z);
        uint2 pv; pv.x = p0; pv.y = p1;
        *(uint2*)(xl + r * 128 + (c4 ^ ((r & 7) << 3))) = pv;
    }
    __syncthreads();

    const int wv  = t >> 6;
    const int l   = t & 63;
    const int l15 = l & 15;
    const int g   = l >> 4;
    const int strip = wv * 16;
    const int arow  = strip + l15;

    f32x4 acc[8];
    #pragma unroll
    for (int i = 0; i < 8; ++i) acc[i] = (f32x4){0.f, 0.f, 0.f, 0.f};

    #pragma unroll
    for (int ks = 0; ks < 4; ++ks) {
        const int k0 = ks * 32 + g * 8;
        short8v a = *(const short8v*)(xl + arow * 128 + (k0 ^ ((arow & 7) << 3)));
        #pragma unroll
        for (int tl = 0; tl < 8; ++tl) {
            short8v b = *(const short8v*)(Wpk + ((size_t)(tl * 4 + ks) * 64 + l) * 8);
            acc[tl] = __builtin_amdgcn_mfma_f32_16x16x32_bf16(a, b, acc[tl], 0, 0, 0);
        }
    }

    float as_t[8], ad_t[8];
    #pragma unroll
    for (int tl = 0; tl < 8; ++tl) {
        as_t[tl] = a_src[tl * 16 + l15];
        ad_t[tl] = a_dst[tl * 16 + l15];
    }

    #pragma unroll
    for (int r = 0; r < 4; ++r) {
        const int n = row0 + strip + g * 4 + r;
        if (n < NN) {
            #pragma unroll
            for (int tl = 0; tl < 8; ++tl)
                hb[(size_t)n * D + tl * 16 + l15] = rne_bf16(acc[tl][r]);
        }
        #pragma unroll
        for (int hd = 0; hd < NH; ++hd) {
            float ps = acc[2*hd][r] * as_t[2*hd] + acc[2*hd+1][r] * as_t[2*hd+1];
            float pd = acc[2*hd][r] * ad_t[2*hd] + acc[2*hd+1][r] * ad_t[2*hd+1];
            #pragma unroll
            for (int off = 1; off < 16; off <<= 1) {
                ps += __shfl_xor(ps, off);
                pd += __shfl_xor(pd, off);
            }
            if (l15 == 0 && n < NN) {
                alpha_s[n * NH + hd] = ps;
                alpha_d[n * NH + hd] = pd;
            }
        }
    }
}

// ---------------- per-dst-node gather + softmax + aggregate + epilogue ------
__global__ __launch_bounds__(256) void gather_kernel(
    const unsigned short* __restrict__ hb, const float* __restrict__ alpha_s,
    const float* __restrict__ alpha_d, const int* __restrict__ row_ptr,
    const unsigned short* __restrict__ srcs, const float* __restrict__ x_in,
    const float* __restrict__ bias, float* __restrict__ out, int apply_act)
{
    const int wave = threadIdx.x >> 6;
    const int lane = threadIdx.x & 63;
    const int half = lane >> 5;
    const int l32  = lane & 31;
    const int head = l32 >> 3;
    const int n = blockIdx.x * 4 + wave;
    if (n >= NN) return;

    const int start = row_ptr[n];
    const int end   = row_ptr[n + 1];
    const float4 ad4 = *(const float4*)&alpha_d[n * NH];

    float4 acc = {0.f, 0.f, 0.f, 0.f};
    float ds0 = 0.f, ds1 = 0.f, ds2 = 0.f, ds3 = 0.f;

    for (int base = start; base < end; base += 64) {
        const int cnt = min(64, end - base);
        int msrc = 0;
        float w0 = 0.f, w1 = 0.f, w2 = 0.f, w3 = 0.f;
        if (lane < cnt) {
            msrc = srcs[base + lane];
            const float4 as4 = *(const float4*)&alpha_s[msrc * NH];
            float e0 = as4.x + ad4.x; e0 = (e0 > 0.f) ? e0 : 0.2f * e0;
            float e1 = as4.y + ad4.y; e1 = (e1 > 0.f) ? e1 : 0.2f * e1;
            float e2 = as4.z + ad4.z; e2 = (e2 > 0.f) ? e2 : 0.2f * e2;
            float e3 = as4.w + ad4.w; e3 = (e3 > 0.f) ? e3 : 0.2f * e3;
            w0 = __expf(e0); w1 = __expf(e1); w2 = __expf(e2); w3 = __expf(e3);
            ds0 += w0; ds1 += w1; ds2 += w2; ds3 += w3;
        }
        for (int m = 0; m < cnt; m += 2) {
            const int me = m + half;
            int s = __shfl(msrc, me);
            float b0 = __shfl(w0, me), b1 = __shfl(w1, me);
            float b2 = __shfl(w2, me), b3 = __shfl(w3, me);
            float ww = (head < 2) ? (head == 0 ? b0 : b1)
                                  : (head == 2 ? b2 : b3);
            const ushort4 hv = *(const ushort4*)(hb + (size_t)s * D + l32 * 4);
            acc.x = fmaf(ww, __uint_as_float((unsigned)hv.x << 16), acc.x);
            acc.y = fmaf(ww, __uint_as_float((unsigned)hv.y << 16), acc.y);
            acc.z = fmaf(ww, __uint_as_float((unsigned)hv.z << 16), acc.z);
            acc.w = fmaf(ww, __uint_as_float((unsigned)hv.w << 16), acc.w);
        }
    }
    acc.x += __shfl_xor(acc.x, 32);
    acc.y += __shfl_xor(acc.y, 32);
    acc.z += __shfl_xor(acc.z, 32);
    acc.w += __shfl_xor(acc.w, 32);
    #pragma unroll
    for (int off = 32; off; off >>= 1) {
        ds0 += __shfl_xor(ds0, off);
        ds1 += __shfl_xor(ds1, off);
        ds2 += __shfl_xor(ds2, off);
        ds3 += __shfl_xor(ds3, off);
    }
    if (half == 0) {
        const float dh = (head == 0) ? ds0 : (head == 1) ? ds1
                       : (head == 2) ? ds2 : ds3;
        const float inv = 1.f / (dh + 1e-16f);
        const size_t off4 = (size_t)n * D + l32 * 4;
        const float4 xi = *(const float4*)(x_in + off4);
        const float4 bi = *(const float4*)(bias + l32 * 4);
        float4 o;
        o.x = acc.x * inv + xi.x + bi.x;
        o.y = acc.y * inv + xi.y + bi.y;
        o.z = acc.z * inv + xi.z + bi.z;
        o.w = acc.w * inv + xi.w + bi.w;
        if (apply_act) {
            o.x = (o.x > 0.f) ? o.x : expm1f(o.x);
            o.y = (o.y > 0.f) ? o.y : expm1f(o.y);
            o.z = (o.z > 0.f) ? o.z : expm1f(o.z);
            o.w = (o.w > 0.f) ? o.w : expm1f(o.w);
        }
        *(float4*)(out + off4) = o;
    }
}

// ---------------------------------------------------------------------------
extern "C" void kernel_launch(void* const* d_in, const int* in_sizes, int n_in,
                              void* d_out, int out_size, void* d_ws, size_t ws_size,
                              hipStream_t stream) {
    const float* x     = (const float*)d_in[0];
    const int*   ei    = (const int*)d_in[1];
    const float* W     = (const float*)d_in[2];
    const float* a_src = (const float*)d_in[3];
    const float* a_dst = (const float*)d_in[4];
    const float* bias  = (const float*)d_in[5];
    float* outp = (float*)d_out;

    const int* e_src = ei;
    const int* e_dst = ei + NE;

    // workspace layout (bytes)
    char* base = (char*)d_ws;
    unsigned short* hb = (unsigned short*)(base);              // NN*D bf16 (12.8MB)
    float* x1      = (float*)(base + 12800000);                // NN*D f32 (25.6MB)
    float* al_s    = (float*)(base + 38400000);                // NN*NH
    float* al_d    = (float*)(base + 39200000);                // NN*NH
    int*   row_ptr = (int*)  (base + 40000000);                // NN+1
    unsigned short* srcs = (unsigned short*)(base + 40200064); // NE ushort (1.6MB)
    unsigned* bukbuf = (unsigned*)(base + 41800064);           // NE uint (3.2MB)
    int*   btot    = (int*)  (base + 45000064);                // NBUK
    int*   bbase   = (int*)  (base + 45001088);                // NBUK
    int*   bwp     = (int*)  (base + 45002112);                // NBUK
    unsigned short* Wpk = (unsigned short*)(base + 45003136);  // 2*2048*8 bf16 (64KB)

    // ---- W repack + CSR build (graph shared by both layers) ----
    repack_kernel<<<16, 256, 0, stream>>>(W, Wpk);
    hipMemsetAsync(btot, 0, NBUK * sizeof(int), stream);
    const int pblocks = (NE + 2047) / 2048;   // 391
    bucket_hist_kernel<<<pblocks, 256, 0, stream>>>(e_dst, btot);
    bucket_scan_kernel<<<1, 256, 0, stream>>>(btot, bbase, bwp, row_ptr);
    partition_kernel<<<pblocks, 256, 0, stream>>>(e_src, e_dst, bwp, bukbuf);
    bucket_sort_kernel<<<NBUK, 256, 0, stream>>>(bukbuf, btot, bbase, row_ptr, srcs);

    const int gemm_blocks   = (NN + 63) / 64;
    const int gather_blocks = (NN + 3) / 4;

    // ---- layer 0 ----
    gemm_alpha_kernel<<<gemm_blocks, 256, 0, stream>>>(x, Wpk, a_src, a_dst,
                                                       hb, al_s, al_d);
    gather_kernel<<<gather_blocks, 256, 0, stream>>>(hb, al_s, al_d, row_ptr, srcs,
                                                     x, bias, x1, 1);
    // ---- layer 1 ----
    gemm_alpha_kernel<<<gemm_blocks, 256, 0, stream>>>(x1, Wpk + 2048 * 8,
                                                       a_src + D, a_dst + D,
                                                       hb, al_s, al_d);
    gather_kernel<<<gather_blocks, 256, 0, stream>>>(hb, al_s, al_d, row_ptr, srcs,
                                                     x1, bias + D, outp, 0);
}

// Round 6
// 166.298 us; speedup vs baseline: 2.6200x; 1.0720x over previous
//
#include <hip/hip_runtime.h>
#include <math.h>

// GAT 2-layer forward. N=50000 nodes, E=800000 edges, D=128, H=4 heads, F=32.
constexpr int NN = 50000;
constexpr int NE = 800000;
constexpr int D  = 128;
constexpr int NH = 4;
constexpr int NBUK = (NN + 255) / 256;   // 196 dst-range buckets of 256 nodes
constexpr int CAP  = 4608;               // max edges/bucket (mean 4096, sigma 64)

typedef __attribute__((ext_vector_type(8))) short short8v;           // 8 bf16
typedef __attribute__((ext_vector_type(8))) unsigned short ushort8v; // 8 bf16 bits
typedef __attribute__((ext_vector_type(4))) float f32x4;             // MFMA acc

__device__ inline unsigned short rne_bf16(float f) {
    unsigned bits = __float_as_uint(f);
    return (unsigned short)((bits + 0x7FFFu + ((bits >> 16) & 1u)) >> 16);
}

// ============== CSR build: two-level bucket sort (once per call) ============
__global__ __launch_bounds__(256) void bucket_hist_kernel(
    const int* __restrict__ dst, int* __restrict__ btot)
{
    __shared__ int c[NBUK];
    for (int i = threadIdx.x; i < NBUK; i += 256) c[i] = 0;
    __syncthreads();
    const int base = blockIdx.x * 2048;
    #pragma unroll
    for (int i = 0; i < 8; ++i) {
        int e = base + i * 256 + threadIdx.x;
        if (e < NE) atomicAdd(&c[dst[e] >> 8], 1);
    }
    __syncthreads();
    for (int i = threadIdx.x; i < NBUK; i += 256)
        if (c[i]) atomicAdd(&btot[i], c[i]);
}

__global__ __launch_bounds__(256) void bucket_scan_kernel(
    const int* __restrict__ btot, int* __restrict__ bbase,
    int* __restrict__ bwp, int* __restrict__ row_ptr)
{
    const int t = threadIdx.x;
    int v = (t < NBUK) ? btot[t] : 0;
    __shared__ int s[256];
    s[t] = v;
    __syncthreads();
    for (int off = 1; off < 256; off <<= 1) {
        int u = (t >= off) ? s[t - off] : 0;
        __syncthreads();
        s[t] += u;
        __syncthreads();
    }
    if (t < NBUK) { int ex = s[t] - v; bbase[t] = ex; bwp[t] = ex; }
    if (t == 0) row_ptr[NN] = NE;
}

__global__ __launch_bounds__(256) void partition_kernel(
    const int* __restrict__ src, const int* __restrict__ dst,
    int* __restrict__ bwp, unsigned* __restrict__ bukbuf)
{
    __shared__ int cnt[NBUK];
    __shared__ int run[NBUK];
    for (int i = threadIdx.x; i < NBUK; i += 256) cnt[i] = 0;
    __syncthreads();
    const int base = blockIdx.x * 2048;
    int s_[8], b_[8], dl_[8];
    #pragma unroll
    for (int i = 0; i < 8; ++i) {
        int e = base + i * 256 + threadIdx.x;
        bool ok = (e < NE);
        s_[i] = ok ? src[e] : 0;
        int d = ok ? dst[e] : 0;
        b_[i] = d >> 8; dl_[i] = d & 255;
        if (ok) atomicAdd(&cnt[b_[i]], 1);
    }
    __syncthreads();
    for (int i = threadIdx.x; i < NBUK; i += 256)
        run[i] = cnt[i] ? atomicAdd(&bwp[i], cnt[i]) : 0;
    __syncthreads();
    #pragma unroll
    for (int i = 0; i < 8; ++i) {
        int e = base + i * 256 + threadIdx.x;
        if (e < NE) {
            int pos = atomicAdd(&run[b_[i]], 1);
            bukbuf[pos] = (unsigned)s_[i] | ((unsigned)dl_[i] << 16);
        }
    }
}

__global__ __launch_bounds__(256) void bucket_sort_kernel(
    const unsigned* __restrict__ bukbuf, const int* __restrict__ btot,
    const int* __restrict__ bbase, int* __restrict__ row_ptr,
    unsigned short* __restrict__ srcs)
{
    const int b = blockIdx.x;
    const int t = threadIdx.x;
    const int cnt = min(btot[b], CAP);
    const int base = bbase[b];
    __shared__ int hist[256];
    __shared__ int run[256];
    __shared__ int s[256];
    __shared__ unsigned short stage[CAP];
    hist[t] = 0;
    __syncthreads();
    for (int i = t; i < cnt; i += 256)
        atomicAdd(&hist[bukbuf[base + i] >> 16], 1);
    __syncthreads();
    int v = hist[t];
    s[t] = v;
    __syncthreads();
    for (int off = 1; off < 256; off <<= 1) {
        int u = (t >= off) ? s[t - off] : 0;
        __syncthreads();
        s[t] += u;
        __syncthreads();
    }
    const int excl = s[t] - v;
    const int node = b * 256 + t;
    if (node < NN) row_ptr[node] = base + excl;
    run[t] = excl;
    __syncthreads();
    for (int i = t; i < cnt; i += 256) {
        unsigned p = bukbuf[base + i];
        int pos = atomicAdd(&run[p >> 16], 1);
        stage[pos] = (unsigned short)(p & 0xFFFFu);
    }
    __syncthreads();
    for (int i = t; i < cnt; i += 256) srcs[base + i] = stage[i];
}

// ---------------- W repack: per-MFMA-fragment bf16 layout ------------------
__global__ __launch_bounds__(256) void repack_kernel(const float* __restrict__ W,
                                                     unsigned short* __restrict__ Wpk) {
    int tid = blockIdx.x * 256 + threadIdx.x;   // 2 layers * 2048 frags
    if (tid >= 2 * 2048) return;
    int layer = tid >> 11;
    int rest  = tid & 2047;
    int tile  = rest >> 8;
    int kstep = (rest >> 6) & 3;
    int lane  = rest & 63;
    int col   = tile * 16 + (lane & 15);
    int kbase = kstep * 32 + (lane >> 4) * 8;
    const float* Wl = W + (size_t)layer * D * D;
    unsigned short v[8];
    #pragma unroll
    for (int j = 0; j < 8; ++j) v[j] = rne_bf16(Wl[(kbase + j) * D + col]);
    *(uint4*)(Wpk + (size_t)tid * 8) = *(const uint4*)v;
}

// ---------------- h = x @ W via MFMA; alphas from f32 accumulator ----------
template<int BF16IN>
__global__ __launch_bounds__(256) void gemm_alpha_kernel(
    const void* __restrict__ xin, const unsigned short* __restrict__ Wpk,
    const float* __restrict__ a_src, const float* __restrict__ a_dst,
    unsigned short* __restrict__ hb, float* __restrict__ alpha_s,
    float* __restrict__ alpha_d)
{
    __shared__ unsigned short xl[64 * 128];   // 16 KB, bf16, XOR-swizzled rows
    const int t = threadIdx.x;
    const int row0 = blockIdx.x * 64;

    if constexpr (BF16IN) {
        const unsigned short* xb = (const unsigned short*)xin;
        #pragma unroll
        for (int it = 0; it < 4; ++it) {
            int idx = it * 256 + t;
            int r   = idx >> 4;
            int c8  = (idx & 15) * 8;
            int n   = row0 + r;
            uint4 v = {0u, 0u, 0u, 0u};
            if (n < NN) v = *(const uint4*)(xb + (size_t)n * D + c8);
            *(uint4*)(xl + r * 128 + (c8 ^ ((r & 7) << 3))) = v;
        }
    } else {
        const float* xf = (const float*)xin;
        #pragma unroll
        for (int it = 0; it < 8; ++it) {
            int idx = it * 256 + t;
            int r   = idx >> 5;
            int c4  = (idx & 31) * 4;
            int n   = row0 + r;
            float4 v;
            if (n < NN) v = *(const float4*)(xf + (size_t)n * D + c4);
            else { v.x = 0.f; v.y = 0.f; v.z = 0.f; v.w = 0.f; }
            unsigned p0 = ((unsigned)rne_bf16(v.y) << 16) | rne_bf16(v.x);
            unsigned p1 = ((unsigned)rne_bf16(v.w) << 16) | rne_bf16(v.z);
            uint2 pv; pv.x = p0; pv.y = p1;
            *(uint2*)(xl + r * 128 + (c4 ^ ((r & 7) << 3))) = pv;
        }
    }
    __syncthreads();

    const int wv  = t >> 6;
    const int l   = t & 63;
    const int l15 = l & 15;
    const int g   = l >> 4;
    const int strip = wv * 16;
    const int arow  = strip + l15;

    f32x4 acc[8];
    #pragma unroll
    for (int i = 0; i < 8; ++i) acc[i] = (f32x4){0.f, 0.f, 0.f, 0.f};

    #pragma unroll
    for (int ks = 0; ks < 4; ++ks) {
        const int k0 = ks * 32 + g * 8;
        short8v a = *(const short8v*)(xl + arow * 128 + (k0 ^ ((arow & 7) << 3)));
        #pragma unroll
        for (int tl = 0; tl < 8; ++tl) {
            short8v b = *(const short8v*)(Wpk + ((size_t)(tl * 4 + ks) * 64 + l) * 8);
            acc[tl] = __builtin_amdgcn_mfma_f32_16x16x32_bf16(a, b, acc[tl], 0, 0, 0);
        }
    }

    float as_t[8], ad_t[8];
    #pragma unroll
    for (int tl = 0; tl < 8; ++tl) {
        as_t[tl] = a_src[tl * 16 + l15];
        ad_t[tl] = a_dst[tl * 16 + l15];
    }

    #pragma unroll
    for (int r = 0; r < 4; ++r) {
        const int n = row0 + strip + g * 4 + r;
        if (n < NN) {
            #pragma unroll
            for (int tl = 0; tl < 8; ++tl)
                hb[(size_t)n * D + tl * 16 + l15] = rne_bf16(acc[tl][r]);
        }
        #pragma unroll
        for (int hd = 0; hd < NH; ++hd) {
            float ps = acc[2*hd][r] * as_t[2*hd] + acc[2*hd+1][r] * as_t[2*hd+1];
            float pd = acc[2*hd][r] * ad_t[2*hd] + acc[2*hd+1][r] * ad_t[2*hd+1];
            #pragma unroll
            for (int off = 1; off < 16; off <<= 1) {
                ps += __shfl_xor(ps, off);
                pd += __shfl_xor(pd, off);
            }
            if (l15 == 0 && n < NN) {
                alpha_s[n * NH + hd] = ps;
                alpha_d[n * NH + hd] = pd;
            }
        }
    }
}

// ---------------- per-dst-node gather + softmax + aggregate + epilogue ------
// One wave per node. Quarter-wave (16 lanes) per edge; lane owns 8 contiguous
// cols (16B ushort8 load). Weights broadcast as packed bf16 (2 dwords) + src.
// Normalization hoisted out of the edge loop (denominator kept f32).
template<int IN_BF16, int OUT_BF16, int ACT>
__global__ __launch_bounds__(256) void gather_kernel(
    const unsigned short* __restrict__ hb, const float* __restrict__ alpha_s,
    const float* __restrict__ alpha_d, const int* __restrict__ row_ptr,
    const unsigned short* __restrict__ srcs, const void* __restrict__ x_in,
    const float* __restrict__ bias, void* __restrict__ out)
{
    const int wave = threadIdx.x >> 6;
    const int lane = threadIdx.x & 63;
    const int q    = lane >> 4;          // edge slot within group-of-4
    const int ql   = lane & 15;          // col group: cols [8*ql, 8*ql+8)
    const int head = ql >> 2;            // all 8 cols share one head
    const int n = blockIdx.x * 4 + wave;
    if (n >= NN) return;

    const int start = row_ptr[n];
    const int end   = row_ptr[n + 1];
    const float4 ad4 = *(const float4*)&alpha_d[n * NH];

    float acc[8];
    #pragma unroll
    for (int c = 0; c < 8; ++c) acc[c] = 0.f;
    float ds0 = 0.f, ds1 = 0.f, ds2 = 0.f, ds3 = 0.f;

    for (int base = start; base < end; base += 64) {
        const int cnt = min(64, end - base);
        int msrc = 0;
        unsigned uw01 = 0, uw23 = 0;
        if (lane < cnt) {
            msrc = srcs[base + lane];
            const float4 as4 = *(const float4*)&alpha_s[msrc * NH];
            float e0 = as4.x + ad4.x; e0 = (e0 > 0.f) ? e0 : 0.2f * e0;
            float e1 = as4.y + ad4.y; e1 = (e1 > 0.f) ? e1 : 0.2f * e1;
            float e2 = as4.z + ad4.z; e2 = (e2 > 0.f) ? e2 : 0.2f * e2;
            float e3 = as4.w + ad4.w; e3 = (e3 > 0.f) ? e3 : 0.2f * e3;
            float w0 = __expf(e0), w1 = __expf(e1);
            float w2 = __expf(e2), w3 = __expf(e3);
            ds0 += w0; ds1 += w1; ds2 += w2; ds3 += w3;
            uw01 = ((unsigned)rne_bf16(w1) << 16) | rne_bf16(w0);
            uw23 = ((unsigned)rne_bf16(w3) << 16) | rne_bf16(w2);
        }
        for (int m = 0; m < cnt; m += 4) {
            const int me = m + q;        // me>=cnt lanes broadcast w=0 -> no-op
            int s = __shfl(msrc, me);
            unsigned b01 = (unsigned)__shfl((int)uw01, me);
            unsigned b23 = (unsigned)__shfl((int)uw23, me);
            unsigned uw = (head < 2) ? b01 : b23;
            float w = __uint_as_float((head & 1) ? (uw & 0xFFFF0000u) : (uw << 16));
            const ushort8v hv = *(const ushort8v*)(hb + (size_t)s * D + ql * 8);
            #pragma unroll
            for (int c = 0; c < 8; ++c)
                acc[c] = fmaf(w, __uint_as_float((unsigned)hv[c] << 16), acc[c]);
        }
    }
    // reduce partial col-sums across the 4 quarter-waves
    #pragma unroll
    for (int c = 0; c < 8; ++c) {
        acc[c] += __shfl_xor(acc[c], 16);
        acc[c] += __shfl_xor(acc[c], 32);
    }
    // reduce denominators across the wave (f32, exact weights)
    #pragma unroll
    for (int off = 32; off; off >>= 1) {
        ds0 += __shfl_xor(ds0, off);
        ds1 += __shfl_xor(ds1, off);
        ds2 += __shfl_xor(ds2, off);
        ds3 += __shfl_xor(ds3, off);
    }
    if (q == 0) {
        const float dh = (head == 0) ? ds0 : (head == 1) ? ds1
                       : (head == 2) ? ds2 : ds3;
        const float inv = 1.f / (dh + 1e-16f);
        const size_t o8 = (size_t)n * D + ql * 8;
        float xi[8];
        if constexpr (IN_BF16) {
            const ushort8v xv = *(const ushort8v*)((const unsigned short*)x_in + o8);
            #pragma unroll
            for (int c = 0; c < 8; ++c)
                xi[c] = __uint_as_float((unsigned)xv[c] << 16);
        } else {
            const float4 a = *(const float4*)((const float*)x_in + o8);
            const float4 b = *(const float4*)((const float*)x_in + o8 + 4);
            xi[0]=a.x; xi[1]=a.y; xi[2]=a.z; xi[3]=a.w;
            xi[4]=b.x; xi[5]=b.y; xi[6]=b.z; xi[7]=b.w;
        }
        const float4 ba = *(const float4*)(bias + ql * 8);
        const float4 bb = *(const float4*)(bias + ql * 8 + 4);
        float bi[8] = {ba.x, ba.y, ba.z, ba.w, bb.x, bb.y, bb.z, bb.w};
        float o[8];
        #pragma unroll
        for (int c = 0; c < 8; ++c) {
            float v = acc[c] * inv + xi[c] + bi[c];
            if constexpr (ACT) v = (v > 0.f) ? v : expm1f(v);
            o[c] = v;
        }
        if constexpr (OUT_BF16) {
            unsigned short ov[8];
            #pragma unroll
            for (int c = 0; c < 8; ++c) ov[c] = rne_bf16(o[c]);
            *(uint4*)((unsigned short*)out + o8) = *(const uint4*)ov;
        } else {
            float4 oa = {o[0], o[1], o[2], o[3]};
            float4 ob = {o[4], o[5], o[6], o[7]};
            *(float4*)((float*)out + o8)     = oa;
            *(float4*)((float*)out + o8 + 4) = ob;
        }
    }
}

// ---------------------------------------------------------------------------
extern "C" void kernel_launch(void* const* d_in, const int* in_sizes, int n_in,
                              void* d_out, int out_size, void* d_ws, size_t ws_size,
                              hipStream_t stream) {
    const float* x     = (const float*)d_in[0];
    const int*   ei    = (const int*)d_in[1];
    const float* W     = (const float*)d_in[2];
    const float* a_src = (const float*)d_in[3];
    const float* a_dst = (const float*)d_in[4];
    const float* bias  = (const float*)d_in[5];
    float* outp = (float*)d_out;

    const int* e_src = ei;
    const int* e_dst = ei + NE;

    // workspace layout (bytes)
    char* base = (char*)d_ws;
    unsigned short* hb  = (unsigned short*)(base);             // NN*D bf16 (12.8MB)
    unsigned short* x1b = (unsigned short*)(base + 12800000);  // NN*D bf16 (12.8MB)
    float* al_s    = (float*)(base + 25600000);                // NN*NH
    float* al_d    = (float*)(base + 26400000);                // NN*NH
    int*   row_ptr = (int*)  (base + 27200000);                // NN+1
    unsigned short* srcs = (unsigned short*)(base + 27400064); // NE ushort (1.6MB)
    unsigned* bukbuf = (unsigned*)(base + 29000064);           // NE uint (3.2MB)
    int*   btot    = (int*)  (base + 32200064);                // NBUK
    int*   bbase   = (int*)  (base + 32201088);                // NBUK
    int*   bwp     = (int*)  (base + 32202112);                // NBUK
    unsigned short* Wpk = (unsigned short*)(base + 32203136);  // 2*2048*8 bf16 (64KB)

    // ---- W repack + CSR build (graph shared by both layers) ----
    repack_kernel<<<16, 256, 0, stream>>>(W, Wpk);
    hipMemsetAsync(btot, 0, NBUK * sizeof(int), stream);
    const int pblocks = (NE + 2047) / 2048;   // 391
    bucket_hist_kernel<<<pblocks, 256, 0, stream>>>(e_dst, btot);
    bucket_scan_kernel<<<1, 256, 0, stream>>>(btot, bbase, bwp, row_ptr);
    partition_kernel<<<pblocks, 256, 0, stream>>>(e_src, e_dst, bwp, bukbuf);
    bucket_sort_kernel<<<NBUK, 256, 0, stream>>>(bukbuf, btot, bbase, row_ptr, srcs);

    const int gemm_blocks   = (NN + 63) / 64;
    const int gather_blocks = (NN + 3) / 4;

    // ---- layer 0 ----
    gemm_alpha_kernel<0><<<gemm_blocks, 256, 0, stream>>>(x, Wpk, a_src, a_dst,
                                                          hb, al_s, al_d);
    gather_kernel<0, 1, 1><<<gather_blocks, 256, 0, stream>>>(
        hb, al_s, al_d, row_ptr, srcs, x, bias, x1b);
    // ---- layer 1 ----
    gemm_alpha_kernel<1><<<gemm_blocks, 256, 0, stream>>>(x1b, Wpk + 2048 * 8,
                                                          a_src + D, a_dst + D,
                                                          hb, al_s, al_d);
    gather_kernel<1, 0, 0><<<gather_blocks, 256, 0, stream>>>(
        hb, al_s, al_d, row_ptr, srcs, x1b, bias + D, outp);
}

// Round 7
// 157.533 us; speedup vs baseline: 2.7658x; 1.0556x over previous
//
#include <hip/hip_runtime.h>
#include <math.h>

// GAT 2-layer forward. N=50000 nodes, E=800000 edges, D=128, H=4 heads, F=32.
constexpr int NN = 50000;
constexpr int NE = 800000;
constexpr int D  = 128;
constexpr int NH = 4;
constexpr int NBUK = (NN + 255) / 256;   // 196 dst-range buckets of 256 nodes
constexpr int CAP  = 4608;               // max edges/bucket (mean ~4082, +8σ)

typedef __attribute__((ext_vector_type(8))) short short8v;  // 8 bf16 (4 VGPR)
typedef __attribute__((ext_vector_type(4))) float f32x4;    // MFMA accumulator

__device__ inline unsigned short rne_bf16(float f) {
    unsigned bits = __float_as_uint(f);
    return (unsigned short)((bits + 0x7FFFu + ((bits >> 16) & 1u)) >> 16);
}

// ============== CSR build: two-level bucket sort (once per call) ============
__global__ __launch_bounds__(256) void bucket_hist_kernel(
    const int* __restrict__ dst, int* __restrict__ btot)
{
    __shared__ int c[NBUK];
    for (int i = threadIdx.x; i < NBUK; i += 256) c[i] = 0;
    __syncthreads();
    const int base = blockIdx.x * 2048;
    #pragma unroll
    for (int i = 0; i < 8; ++i) {
        int e = base + i * 256 + threadIdx.x;
        if (e < NE) atomicAdd(&c[dst[e] >> 8], 1);
    }
    __syncthreads();
    for (int i = threadIdx.x; i < NBUK; i += 256)
        if (c[i]) atomicAdd(&btot[i], c[i]);
}

__global__ __launch_bounds__(256) void bucket_scan_kernel(
    const int* __restrict__ btot, int* __restrict__ bbase,
    int* __restrict__ bwp, int* __restrict__ row_ptr)
{
    const int t = threadIdx.x;
    int v = (t < NBUK) ? btot[t] : 0;
    __shared__ int s[256];
    s[t] = v;
    __syncthreads();
    for (int off = 1; off < 256; off <<= 1) {
        int u = (t >= off) ? s[t - off] : 0;
        __syncthreads();
        s[t] += u;
        __syncthreads();
    }
    if (t < NBUK) { int ex = s[t] - v; bbase[t] = ex; bwp[t] = ex; }
    if (t == 0) row_ptr[NN] = NE;
}

__global__ __launch_bounds__(256) void partition_kernel(
    const int* __restrict__ src, const int* __restrict__ dst,
    int* __restrict__ bwp, unsigned* __restrict__ bukbuf)
{
    __shared__ int cnt[NBUK];
    __shared__ int run[NBUK];
    for (int i = threadIdx.x; i < NBUK; i += 256) cnt[i] = 0;
    __syncthreads();
    const int base = blockIdx.x * 2048;
    int s_[8], b_[8], dl_[8];
    #pragma unroll
    for (int i = 0; i < 8; ++i) {
        int e = base + i * 256 + threadIdx.x;
        bool ok = (e < NE);
        s_[i] = ok ? src[e] : 0;
        int d = ok ? dst[e] : 0;
        b_[i] = d >> 8; dl_[i] = d & 255;
        if (ok) atomicAdd(&cnt[b_[i]], 1);
    }
    __syncthreads();
    for (int i = threadIdx.x; i < NBUK; i += 256)
        run[i] = cnt[i] ? atomicAdd(&bwp[i], cnt[i]) : 0;
    __syncthreads();
    #pragma unroll
    for (int i = 0; i < 8; ++i) {
        int e = base + i * 256 + threadIdx.x;
        if (e < NE) {
            int pos = atomicAdd(&run[b_[i]], 1);
            bukbuf[pos] = (unsigned)s_[i] | ((unsigned)dl_[i] << 16);
        }
    }
}

__global__ __launch_bounds__(256) void bucket_sort_kernel(
    const unsigned* __restrict__ bukbuf, const int* __restrict__ btot,
    const int* __restrict__ bbase, int* __restrict__ row_ptr,
    unsigned short* __restrict__ srcs)
{
    const int b = blockIdx.x;
    const int t = threadIdx.x;
    const int cnt = min(btot[b], CAP);
    const int base = bbase[b];
    __shared__ int hist[256];
    __shared__ int run[256];
    __shared__ int s[256];
    __shared__ unsigned short stage[CAP];
    hist[t] = 0;
    __syncthreads();
    for (int i = t; i < cnt; i += 256)
        atomicAdd(&hist[bukbuf[base + i] >> 16], 1);
    __syncthreads();
    int v = hist[t];
    s[t] = v;
    __syncthreads();
    for (int off = 1; off < 256; off <<= 1) {
        int u = (t >= off) ? s[t - off] : 0;
        __syncthreads();
        s[t] += u;
        __syncthreads();
    }
    const int excl = s[t] - v;
    const int node = b * 256 + t;
    if (node < NN) row_ptr[node] = base + excl;
    run[t] = excl;
    __syncthreads();
    for (int i = t; i < cnt; i += 256) {
        unsigned p = bukbuf[base + i];
        int pos = atomicAdd(&run[p >> 16], 1);
        stage[pos] = (unsigned short)(p & 0xFFFFu);
    }
    __syncthreads();
    for (int i = t; i < cnt; i += 256) srcs[base + i] = stage[i];
}

// ---------------- W repack: per-MFMA-fragment bf16 layout ------------------
__global__ __launch_bounds__(256) void repack_kernel(const float* __restrict__ W,
                                                     unsigned short* __restrict__ Wpk) {
    int tid = blockIdx.x * 256 + threadIdx.x;   // 2 layers * 2048 frags
    if (tid >= 2 * 2048) return;
    int layer = tid >> 11;
    int rest  = tid & 2047;
    int tile  = rest >> 8;
    int kstep = (rest >> 6) & 3;
    int lane  = rest & 63;
    int col   = tile * 16 + (lane & 15);
    int kbase = kstep * 32 + (lane >> 4) * 8;
    const float* Wl = W + (size_t)layer * D * D;
    unsigned short v[8];
    #pragma unroll
    for (int j = 0; j < 8; ++j) v[j] = rne_bf16(Wl[(kbase + j) * D + col]);
    *(uint4*)(Wpk + (size_t)tid * 8) = *(const uint4*)v;
}

// ---------------- h = x @ W via MFMA; alphas from f32 accumulator ----------
template<int BF16IN>
__global__ __launch_bounds__(256) void gemm_alpha_kernel(
    const void* __restrict__ xin, const unsigned short* __restrict__ Wpk,
    const float* __restrict__ a_src, const float* __restrict__ a_dst,
    unsigned short* __restrict__ hb, float* __restrict__ alpha_s,
    float* __restrict__ alpha_d)
{
    __shared__ unsigned short xl[64 * 128];   // 16 KB, bf16, XOR-swizzled rows
    const int t = threadIdx.x;
    const int row0 = blockIdx.x * 64;

    if constexpr (BF16IN) {
        const unsigned short* xb = (const unsigned short*)xin;
        #pragma unroll
        for (int it = 0; it < 4; ++it) {
            int idx = it * 256 + t;
            int r   = idx >> 4;
            int c8  = (idx & 15) * 8;
            int n   = row0 + r;
            uint4 v = {0u, 0u, 0u, 0u};
            if (n < NN) v = *(const uint4*)(xb + (size_t)n * D + c8);
            *(uint4*)(xl + r * 128 + (c8 ^ ((r & 7) << 3))) = v;
        }
    } else {
        const float* xf = (const float*)xin;
        #pragma unroll
        for (int it = 0; it < 8; ++it) {
            int idx = it * 256 + t;
            int r   = idx >> 5;
            int c4  = (idx & 31) * 4;
            int n   = row0 + r;
            float4 v;
            if (n < NN) v = *(const float4*)(xf + (size_t)n * D + c4);
            else { v.x = 0.f; v.y = 0.f; v.z = 0.f; v.w = 0.f; }
            unsigned p0 = ((unsigned)rne_bf16(v.y) << 16) | rne_bf16(v.x);
            unsigned p1 = ((unsigned)rne_bf16(v.w) << 16) | rne_bf16(v.z);
            uint2 pv; pv.x = p0; pv.y = p1;
            *(uint2*)(xl + r * 128 + (c4 ^ ((r & 7) << 3))) = pv;
        }
    }
    __syncthreads();

    const int wv  = t >> 6;
    const int l   = t & 63;
    const int l15 = l & 15;
    const int g   = l >> 4;
    const int strip = wv * 16;
    const int arow  = strip + l15;

    f32x4 acc[8];
    #pragma unroll
    for (int i = 0; i < 8; ++i) acc[i] = (f32x4){0.f, 0.f, 0.f, 0.f};

    #pragma unroll
    for (int ks = 0; ks < 4; ++ks) {
        const int k0 = ks * 32 + g * 8;
        short8v a = *(const short8v*)(xl + arow * 128 + (k0 ^ ((arow & 7) << 3)));
        #pragma unroll
        for (int tl = 0; tl < 8; ++tl) {
            short8v b = *(const short8v*)(Wpk + ((size_t)(tl * 4 + ks) * 64 + l) * 8);
            acc[tl] = __builtin_amdgcn_mfma_f32_16x16x32_bf16(a, b, acc[tl], 0, 0, 0);
        }
    }

    float as_t[8], ad_t[8];
    #pragma unroll
    for (int tl = 0; tl < 8; ++tl) {
        as_t[tl] = a_src[tl * 16 + l15];
        ad_t[tl] = a_dst[tl * 16 + l15];
    }

    #pragma unroll
    for (int r = 0; r < 4; ++r) {
        const int n = row0 + strip + g * 4 + r;
        if (n < NN) {
            #pragma unroll
            for (int tl = 0; tl < 8; ++tl)
                hb[(size_t)n * D + tl * 16 + l15] = rne_bf16(acc[tl][r]);
        }
        #pragma unroll
        for (int hd = 0; hd < NH; ++hd) {
            float ps = acc[2*hd][r] * as_t[2*hd] + acc[2*hd+1][r] * as_t[2*hd+1];
            float pd = acc[2*hd][r] * ad_t[2*hd] + acc[2*hd+1][r] * ad_t[2*hd+1];
            #pragma unroll
            for (int off = 1; off < 16; off <<= 1) {
                ps += __shfl_xor(ps, off);
                pd += __shfl_xor(pd, off);
            }
            if (l15 == 0 && n < NN) {
                alpha_s[n * NH + hd] = ps;
                alpha_d[n * NH + hd] = pd;
            }
        }
    }
}

// ---------------- per-dst-node gather + softmax + aggregate + epilogue ------
// One wave per node; quarter-wave (16 lanes) per edge; lane owns 8 cols.
// Denominator rides the inner loop (den += w, same bf16 weights as numerator)
// and the same xor16/xor32 reduce as the accumulators. After the full reduce
// EVERY lane holds complete col sums, so lane (q,ql) writes cols 8ql+2q..+1:
// all 64 lanes active in the epilogue, no divergence.
template<int IN_BF16, int OUT_BF16, int ACT>
__global__ __launch_bounds__(256) void gather_kernel(
    const unsigned short* __restrict__ hb, const float* __restrict__ alpha_s,
    const float* __restrict__ alpha_d, const int* __restrict__ row_ptr,
    const unsigned short* __restrict__ srcs, const void* __restrict__ x_in,
    const float* __restrict__ bias, void* __restrict__ out)
{
    const int wave = threadIdx.x >> 6;
    const int lane = threadIdx.x & 63;
    const int q    = lane >> 4;          // edge slot within group-of-4
    const int ql   = lane & 15;          // col group: cols [8*ql, 8*ql+8)
    const int head = ql >> 2;            // all 8 cols share one head
    const int n = blockIdx.x * 4 + wave;
    if (n >= NN) return;

    const int start = row_ptr[n];
    const int end   = row_ptr[n + 1];
    const float4 ad4 = *(const float4*)&alpha_d[n * NH];

    float acc[8];
    #pragma unroll
    for (int c = 0; c < 8; ++c) acc[c] = 0.f;
    float den = 0.f;

    for (int base = start; base < end; base += 64) {
        const int cnt = min(64, end - base);
        int msrc = 0;
        unsigned uw01 = 0, uw23 = 0;
        if (lane < cnt) {
            msrc = srcs[base + lane];
            const float4 as4 = *(const float4*)&alpha_s[msrc * NH];
            float e0 = as4.x + ad4.x; e0 = (e0 > 0.f) ? e0 : 0.2f * e0;
            float e1 = as4.y + ad4.y; e1 = (e1 > 0.f) ? e1 : 0.2f * e1;
            float e2 = as4.z + ad4.z; e2 = (e2 > 0.f) ? e2 : 0.2f * e2;
            float e3 = as4.w + ad4.w; e3 = (e3 > 0.f) ? e3 : 0.2f * e3;
            float w0 = __expf(e0), w1 = __expf(e1);
            float w2 = __expf(e2), w3 = __expf(e3);
            uw01 = ((unsigned)rne_bf16(w1) << 16) | rne_bf16(w0);
            uw23 = ((unsigned)rne_bf16(w3) << 16) | rne_bf16(w2);
        }
        for (int m = 0; m < cnt; m += 4) {
            const int me = m + q;        // me>=cnt lanes broadcast w=0 -> no-op
            int s = __shfl(msrc, me);
            unsigned b01 = (unsigned)__shfl((int)uw01, me);
            unsigned b23 = (unsigned)__shfl((int)uw23, me);
            unsigned uw = (head < 2) ? b01 : b23;
            float w = __uint_as_float((head & 1) ? (uw & 0xFFFF0000u) : (uw << 16));
            den += w;
            const uint4 hv = *(const uint4*)(hb + (size_t)s * D + ql * 8);
            acc[0] = fmaf(w, __uint_as_float(hv.x << 16),          acc[0]);
            acc[1] = fmaf(w, __uint_as_float(hv.x & 0xFFFF0000u),  acc[1]);
            acc[2] = fmaf(w, __uint_as_float(hv.y << 16),          acc[2]);
            acc[3] = fmaf(w, __uint_as_float(hv.y & 0xFFFF0000u),  acc[3]);
            acc[4] = fmaf(w, __uint_as_float(hv.z << 16),          acc[4]);
            acc[5] = fmaf(w, __uint_as_float(hv.z & 0xFFFF0000u),  acc[5]);
            acc[6] = fmaf(w, __uint_as_float(hv.w << 16),          acc[6]);
            acc[7] = fmaf(w, __uint_as_float(hv.w & 0xFFFF0000u),  acc[7]);
        }
    }
    // full reduce across the 4 quarter-waves: every lane gets complete sums
    #pragma unroll
    for (int c = 0; c < 8; ++c) {
        acc[c] += __shfl_xor(acc[c], 16);
        acc[c] += __shfl_xor(acc[c], 32);
    }
    den += __shfl_xor(den, 16);
    den += __shfl_xor(den, 32);

    // epilogue: lane (q,ql) owns cols c0 = 8*ql + 2*q, c0+1
    const float inv = 1.f / (den + 1e-16f);
    const int c0 = ql * 8 + q * 2;
    const size_t o2 = (size_t)n * D + c0;
    float xi0, xi1;
    if constexpr (IN_BF16) {
        unsigned xv = *(const unsigned*)((const unsigned short*)x_in + o2);
        xi0 = __uint_as_float(xv << 16);
        xi1 = __uint_as_float(xv & 0xFFFF0000u);
    } else {
        const float2 xv = *(const float2*)((const float*)x_in + o2);
        xi0 = xv.x; xi1 = xv.y;
    }
    const float2 bi = *(const float2*)(bias + c0);
    float v0 = fmaf(acc[q * 2],     inv, xi0) + bi.x;
    float v1 = fmaf(acc[q * 2 + 1], inv, xi1) + bi.y;
    if constexpr (ACT) {
        v0 = (v0 > 0.f) ? v0 : (__expf(v0) - 1.f);
        v1 = (v1 > 0.f) ? v1 : (__expf(v1) - 1.f);
    }
    if constexpr (OUT_BF16) {
        unsigned ov = ((unsigned)rne_bf16(v1) << 16) | rne_bf16(v0);
        *(unsigned*)((unsigned short*)out + o2) = ov;
    } else {
        float2 o; o.x = v0; o.y = v1;
        *(float2*)((float*)out + o2) = o;
    }
}

// ---------------------------------------------------------------------------
extern "C" void kernel_launch(void* const* d_in, const int* in_sizes, int n_in,
                              void* d_out, int out_size, void* d_ws, size_t ws_size,
                              hipStream_t stream) {
    const float* x     = (const float*)d_in[0];
    const int*   ei    = (const int*)d_in[1];
    const float* W     = (const float*)d_in[2];
    const float* a_src = (const float*)d_in[3];
    const float* a_dst = (const float*)d_in[4];
    const float* bias  = (const float*)d_in[5];
    float* outp = (float*)d_out;

    const int* e_src = ei;
    const int* e_dst = ei + NE;

    // workspace layout (bytes)
    char* base = (char*)d_ws;
    unsigned short* hb  = (unsigned short*)(base);             // NN*D bf16 (12.8MB)
    unsigned short* x1b = (unsigned short*)(base + 12800000);  // NN*D bf16 (12.8MB)
    float* al_s    = (float*)(base + 25600000);                // NN*NH
    float* al_d    = (float*)(base + 26400000);                // NN*NH
    int*   row_ptr = (int*)  (base + 27200000);                // NN+1
    unsigned short* srcs = (unsigned short*)(base + 27400064); // NE ushort (1.6MB)
    unsigned* bukbuf = (unsigned*)(base + 29000064);           // NE uint (3.2MB)
    int*   btot    = (int*)  (base + 32200064);                // NBUK
    int*   bbase   = (int*)  (base + 32201088);                // NBUK
    int*   bwp     = (int*)  (base + 32202112);                // NBUK
    unsigned short* Wpk = (unsigned short*)(base + 32203136);  // 2*2048*8 bf16 (64KB)

    // ---- W repack + CSR build (graph shared by both layers) ----
    repack_kernel<<<16, 256, 0, stream>>>(W, Wpk);
    hipMemsetAsync(btot, 0, NBUK * sizeof(int), stream);
    const int pblocks = (NE + 2047) / 2048;   // 391
    bucket_hist_kernel<<<pblocks, 256, 0, stream>>>(e_dst, btot);
    bucket_scan_kernel<<<1, 256, 0, stream>>>(btot, bbase, bwp, row_ptr);
    partition_kernel<<<pblocks, 256, 0, stream>>>(e_src, e_dst, bwp, bukbuf);
    bucket_sort_kernel<<<NBUK, 256, 0, stream>>>(bukbuf, btot, bbase, row_ptr, srcs);

    const int gemm_blocks   = (NN + 63) / 64;
    const int gather_blocks = (NN + 3) / 4;

    // ---- layer 0 ----
    gemm_alpha_kernel<0><<<gemm_blocks, 256, 0, stream>>>(x, Wpk, a_src, a_dst,
                                                          hb, al_s, al_d);
    gather_kernel<0, 1, 1><<<gather_blocks, 256, 0, stream>>>(
        hb, al_s, al_d, row_ptr, srcs, x, bias, x1b);
    // ---- layer 1 ----
    gemm_alpha_kernel<1><<<gemm_blocks, 256, 0, stream>>>(x1b, Wpk + 2048 * 8,
                                                          a_src + D, a_dst + D,
                                                          hb, al_s, al_d);
    gather_kernel<1, 0, 0><<<gather_blocks, 256, 0, stream>>>(
        hb, al_s, al_d, row_ptr, srcs, x1b, bias + D, outp);
}

// Round 8
// 155.538 us; speedup vs baseline: 2.8013x; 1.0128x over previous
//
#include <hip/hip_runtime.h>
#include <math.h>

// GAT 2-layer forward. N=50000 nodes, E=800000 edges, D=128, H=4 heads, F=32.
constexpr int NN = 50000;
constexpr int NE = 800000;
constexpr int D  = 128;
constexpr int NH = 4;
constexpr int NBUK = (NN + 255) / 256;   // 196 dst-range buckets of 256 nodes
constexpr int CAP  = 4608;               // max edges/bucket (mean ~4082, +8σ)

typedef __attribute__((ext_vector_type(8))) short short8v;  // 8 bf16 (4 VGPR)
typedef __attribute__((ext_vector_type(4))) float f32x4;    // MFMA accumulator

__device__ inline unsigned short rne_bf16(float f) {
    unsigned bits = __float_as_uint(f);
    return (unsigned short)((bits + 0x7FFFu + ((bits >> 16) & 1u)) >> 16);
}

// ============== CSR build: two-level bucket sort (once per call) ============
__global__ __launch_bounds__(256) void bucket_hist_kernel(
    const int* __restrict__ dst, int* __restrict__ btot)
{
    __shared__ int c[NBUK];
    for (int i = threadIdx.x; i < NBUK; i += 256) c[i] = 0;
    __syncthreads();
    const int base = blockIdx.x * 2048;
    #pragma unroll
    for (int i = 0; i < 8; ++i) {
        int e = base + i * 256 + threadIdx.x;
        if (e < NE) atomicAdd(&c[dst[e] >> 8], 1);
    }
    __syncthreads();
    for (int i = threadIdx.x; i < NBUK; i += 256)
        if (c[i]) atomicAdd(&btot[i], c[i]);
}

__global__ __launch_bounds__(256) void bucket_scan_kernel(
    const int* __restrict__ btot, int* __restrict__ bbase,
    int* __restrict__ bwp, int* __restrict__ row_ptr)
{
    const int t = threadIdx.x;
    int v = (t < NBUK) ? btot[t] : 0;
    __shared__ int s[256];
    s[t] = v;
    __syncthreads();
    for (int off = 1; off < 256; off <<= 1) {
        int u = (t >= off) ? s[t - off] : 0;
        __syncthreads();
        s[t] += u;
        __syncthreads();
    }
    if (t < NBUK) { int ex = s[t] - v; bbase[t] = ex; bwp[t] = ex; }
    if (t == 0) row_ptr[NN] = NE;
}

__global__ __launch_bounds__(256) void partition_kernel(
    const int* __restrict__ src, const int* __restrict__ dst,
    int* __restrict__ bwp, unsigned* __restrict__ bukbuf)
{
    __shared__ int cnt[NBUK];
    __shared__ int run[NBUK];
    for (int i = threadIdx.x; i < NBUK; i += 256) cnt[i] = 0;
    __syncthreads();
    const int base = blockIdx.x * 2048;
    int s_[8], b_[8], dl_[8];
    #pragma unroll
    for (int i = 0; i < 8; ++i) {
        int e = base + i * 256 + threadIdx.x;
        bool ok = (e < NE);
        s_[i] = ok ? src[e] : 0;
        int d = ok ? dst[e] : 0;
        b_[i] = d >> 8; dl_[i] = d & 255;
        if (ok) atomicAdd(&cnt[b_[i]], 1);
    }
    __syncthreads();
    for (int i = threadIdx.x; i < NBUK; i += 256)
        run[i] = cnt[i] ? atomicAdd(&bwp[i], cnt[i]) : 0;
    __syncthreads();
    #pragma unroll
    for (int i = 0; i < 8; ++i) {
        int e = base + i * 256 + threadIdx.x;
        if (e < NE) {
            int pos = atomicAdd(&run[b_[i]], 1);
            bukbuf[pos] = (unsigned)s_[i] | ((unsigned)dl_[i] << 16);
        }
    }
}

__global__ __launch_bounds__(256) void bucket_sort_kernel(
    const unsigned* __restrict__ bukbuf, const int* __restrict__ btot,
    const int* __restrict__ bbase, int* __restrict__ row_ptr,
    unsigned short* __restrict__ srcs)
{
    const int b = blockIdx.x;
    const int t = threadIdx.x;
    const int cnt = min(btot[b], CAP);
    const int base = bbase[b];
    __shared__ int hist[256];
    __shared__ int run[256];
    __shared__ int s[256];
    __shared__ unsigned short stage[CAP];
    hist[t] = 0;
    __syncthreads();
    for (int i = t; i < cnt; i += 256)
        atomicAdd(&hist[bukbuf[base + i] >> 16], 1);
    __syncthreads();
    int v = hist[t];
    s[t] = v;
    __syncthreads();
    for (int off = 1; off < 256; off <<= 1) {
        int u = (t >= off) ? s[t - off] : 0;
        __syncthreads();
        s[t] += u;
        __syncthreads();
    }
    const int excl = s[t] - v;
    const int node = b * 256 + t;
    if (node < NN) row_ptr[node] = base + excl;
    run[t] = excl;
    __syncthreads();
    for (int i = t; i < cnt; i += 256) {
        unsigned p = bukbuf[base + i];
        int pos = atomicAdd(&run[p >> 16], 1);
        stage[pos] = (unsigned short)(p & 0xFFFFu);
    }
    __syncthreads();
    for (int i = t; i < cnt; i += 256) srcs[base + i] = stage[i];
}

// ------- W repack (per-MFMA-fragment bf16 layout) + btot zeroing -----------
// Block 0 also zeroes btot: this kernel precedes bucket_hist in stream order,
// replacing a hipMemsetAsync whose fillBuffer dispatch cost ~42us per replay.
__global__ __launch_bounds__(256) void repack_kernel(const float* __restrict__ W,
                                                     unsigned short* __restrict__ Wpk,
                                                     int* __restrict__ btot) {
    if (blockIdx.x == 0 && threadIdx.x < NBUK) btot[threadIdx.x] = 0;
    int tid = blockIdx.x * 256 + threadIdx.x;   // 2 layers * 2048 frags
    if (tid >= 2 * 2048) return;
    int layer = tid >> 11;
    int rest  = tid & 2047;
    int tile  = rest >> 8;
    int kstep = (rest >> 6) & 3;
    int lane  = rest & 63;
    int col   = tile * 16 + (lane & 15);
    int kbase = kstep * 32 + (lane >> 4) * 8;
    const float* Wl = W + (size_t)layer * D * D;
    unsigned short v[8];
    #pragma unroll
    for (int j = 0; j < 8; ++j) v[j] = rne_bf16(Wl[(kbase + j) * D + col]);
    *(uint4*)(Wpk + (size_t)tid * 8) = *(const uint4*)v;
}

// ---------------- h = x @ W via MFMA; alphas from f32 accumulator ----------
template<int BF16IN>
__global__ __launch_bounds__(256) void gemm_alpha_kernel(
    const void* __restrict__ xin, const unsigned short* __restrict__ Wpk,
    const float* __restrict__ a_src, const float* __restrict__ a_dst,
    unsigned short* __restrict__ hb, float* __restrict__ alpha_s,
    float* __restrict__ alpha_d)
{
    __shared__ unsigned short xl[64 * 128];   // 16 KB, bf16, XOR-swizzled rows
    const int t = threadIdx.x;
    const int row0 = blockIdx.x * 64;

    if constexpr (BF16IN) {
        const unsigned short* xb = (const unsigned short*)xin;
        #pragma unroll
        for (int it = 0; it < 4; ++it) {
            int idx = it * 256 + t;
            int r   = idx >> 4;
            int c8  = (idx & 15) * 8;
            int n   = row0 + r;
            uint4 v = {0u, 0u, 0u, 0u};
            if (n < NN) v = *(const uint4*)(xb + (size_t)n * D + c8);
            *(uint4*)(xl + r * 128 + (c8 ^ ((r & 7) << 3))) = v;
        }
    } else {
        const float* xf = (const float*)xin;
        #pragma unroll
        for (int it = 0; it < 8; ++it) {
            int idx = it * 256 + t;
            int r   = idx >> 5;
            int c4  = (idx & 31) * 4;
            int n   = row0 + r;
            float4 v;
            if (n < NN) v = *(const float4*)(xf + (size_t)n * D + c4);
            else { v.x = 0.f; v.y = 0.f; v.z = 0.f; v.w = 0.f; }
            unsigned p0 = ((unsigned)rne_bf16(v.y) << 16) | rne_bf16(v.x);
            unsigned p1 = ((unsigned)rne_bf16(v.w) << 16) | rne_bf16(v.z);
            uint2 pv; pv.x = p0; pv.y = p1;
            *(uint2*)(xl + r * 128 + (c4 ^ ((r & 7) << 3))) = pv;
        }
    }
    __syncthreads();

    const int wv  = t >> 6;
    const int l   = t & 63;
    const int l15 = l & 15;
    const int g   = l >> 4;
    const int strip = wv * 16;
    const int arow  = strip + l15;

    f32x4 acc[8];
    #pragma unroll
    for (int i = 0; i < 8; ++i) acc[i] = (f32x4){0.f, 0.f, 0.f, 0.f};

    #pragma unroll
    for (int ks = 0; ks < 4; ++ks) {
        const int k0 = ks * 32 + g * 8;
        short8v a = *(const short8v*)(xl + arow * 128 + (k0 ^ ((arow & 7) << 3)));
        #pragma unroll
        for (int tl = 0; tl < 8; ++tl) {
            short8v b = *(const short8v*)(Wpk + ((size_t)(tl * 4 + ks) * 64 + l) * 8);
            acc[tl] = __builtin_amdgcn_mfma_f32_16x16x32_bf16(a, b, acc[tl], 0, 0, 0);
        }
    }

    float as_t[8], ad_t[8];
    #pragma unroll
    for (int tl = 0; tl < 8; ++tl) {
        as_t[tl] = a_src[tl * 16 + l15];
        ad_t[tl] = a_dst[tl * 16 + l15];
    }

    #pragma unroll
    for (int r = 0; r < 4; ++r) {
        const int n = row0 + strip + g * 4 + r;
        if (n < NN) {
            #pragma unroll
            for (int tl = 0; tl < 8; ++tl)
                hb[(size_t)n * D + tl * 16 + l15] = rne_bf16(acc[tl][r]);
        }
        #pragma unroll
        for (int hd = 0; hd < NH; ++hd) {
            float ps = acc[2*hd][r] * as_t[2*hd] + acc[2*hd+1][r] * as_t[2*hd+1];
            float pd = acc[2*hd][r] * ad_t[2*hd] + acc[2*hd+1][r] * ad_t[2*hd+1];
            #pragma unroll
            for (int off = 1; off < 16; off <<= 1) {
                ps += __shfl_xor(ps, off);
                pd += __shfl_xor(pd, off);
            }
            if (l15 == 0 && n < NN) {
                alpha_s[n * NH + hd] = ps;
                alpha_d[n * NH + hd] = pd;
            }
        }
    }
}

// ---------------- per-dst-node gather + softmax + aggregate + epilogue ------
// One wave per node; quarter-wave (16 lanes) per edge; lane owns 8 cols.
// Denominator rides the inner loop and the same xor16/xor32 reduce as the
// accumulators; epilogue runs on all 64 lanes (2 cols each), no divergence.
template<int IN_BF16, int OUT_BF16, int ACT>
__global__ __launch_bounds__(256) void gather_kernel(
    const unsigned short* __restrict__ hb, const float* __restrict__ alpha_s,
    const float* __restrict__ alpha_d, const int* __restrict__ row_ptr,
    const unsigned short* __restrict__ srcs, const void* __restrict__ x_in,
    const float* __restrict__ bias, void* __restrict__ out)
{
    const int wave = threadIdx.x >> 6;
    const int lane = threadIdx.x & 63;
    const int q    = lane >> 4;          // edge slot within group-of-4
    const int ql   = lane & 15;          // col group: cols [8*ql, 8*ql+8)
    const int head = ql >> 2;            // all 8 cols share one head
    const int n = blockIdx.x * 4 + wave;
    if (n >= NN) return;

    const int start = row_ptr[n];
    const int end   = row_ptr[n + 1];
    const float4 ad4 = *(const float4*)&alpha_d[n * NH];

    float acc[8];
    #pragma unroll
    for (int c = 0; c < 8; ++c) acc[c] = 0.f;
    float den = 0.f;

    for (int base = start; base < end; base += 64) {
        const int cnt = min(64, end - base);
        int msrc = 0;
        unsigned uw01 = 0, uw23 = 0;
        if (lane < cnt) {
            msrc = srcs[base + lane];
            const float4 as4 = *(const float4*)&alpha_s[msrc * NH];
            float e0 = as4.x + ad4.x; e0 = (e0 > 0.f) ? e0 : 0.2f * e0;
            float e1 = as4.y + ad4.y; e1 = (e1 > 0.f) ? e1 : 0.2f * e1;
            float e2 = as4.z + ad4.z; e2 = (e2 > 0.f) ? e2 : 0.2f * e2;
            float e3 = as4.w + ad4.w; e3 = (e3 > 0.f) ? e3 : 0.2f * e3;
            float w0 = __expf(e0), w1 = __expf(e1);
            float w2 = __expf(e2), w3 = __expf(e3);
            uw01 = ((unsigned)rne_bf16(w1) << 16) | rne_bf16(w0);
            uw23 = ((unsigned)rne_bf16(w3) << 16) | rne_bf16(w2);
        }
        for (int m = 0; m < cnt; m += 4) {
            const int me = m + q;        // me>=cnt lanes broadcast w=0 -> no-op
            int s = __shfl(msrc, me);
            unsigned b01 = (unsigned)__shfl((int)uw01, me);
            unsigned b23 = (unsigned)__shfl((int)uw23, me);
            unsigned uw = (head < 2) ? b01 : b23;
            float w = __uint_as_float((head & 1) ? (uw & 0xFFFF0000u) : (uw << 16));
            den += w;
            const uint4 hv = *(const uint4*)(hb + (size_t)s * D + ql * 8);
            acc[0] = fmaf(w, __uint_as_float(hv.x << 16),          acc[0]);
            acc[1] = fmaf(w, __uint_as_float(hv.x & 0xFFFF0000u),  acc[1]);
            acc[2] = fmaf(w, __uint_as_float(hv.y << 16),          acc[2]);
            acc[3] = fmaf(w, __uint_as_float(hv.y & 0xFFFF0000u),  acc[3]);
            acc[4] = fmaf(w, __uint_as_float(hv.z << 16),          acc[4]);
            acc[5] = fmaf(w, __uint_as_float(hv.z & 0xFFFF0000u),  acc[5]);
            acc[6] = fmaf(w, __uint_as_float(hv.w << 16),          acc[6]);
            acc[7] = fmaf(w, __uint_as_float(hv.w & 0xFFFF0000u),  acc[7]);
        }
    }
    // full reduce across the 4 quarter-waves: every lane gets complete sums
    #pragma unroll
    for (int c = 0; c < 8; ++c) {
        acc[c] += __shfl_xor(acc[c], 16);
        acc[c] += __shfl_xor(acc[c], 32);
    }
    den += __shfl_xor(den, 16);
    den += __shfl_xor(den, 32);

    // epilogue: lane (q,ql) owns cols c0 = 8*ql + 2*q, c0+1
    const float inv = 1.f / (den + 1e-16f);
    const int c0 = ql * 8 + q * 2;
    const size_t o2 = (size_t)n * D + c0;
    float xi0, xi1;
    if constexpr (IN_BF16) {
        unsigned xv = *(const unsigned*)((const unsigned short*)x_in + o2);
        xi0 = __uint_as_float(xv << 16);
        xi1 = __uint_as_float(xv & 0xFFFF0000u);
    } else {
        const float2 xv = *(const float2*)((const float*)x_in + o2);
        xi0 = xv.x; xi1 = xv.y;
    }
    const float2 bi = *(const float2*)(bias + c0);
    float v0 = fmaf(acc[q * 2],     inv, xi0) + bi.x;
    float v1 = fmaf(acc[q * 2 + 1], inv, xi1) + bi.y;
    if constexpr (ACT) {
        v0 = (v0 > 0.f) ? v0 : (__expf(v0) - 1.f);
        v1 = (v1 > 0.f) ? v1 : (__expf(v1) - 1.f);
    }
    if constexpr (OUT_BF16) {
        unsigned ov = ((unsigned)rne_bf16(v1) << 16) | rne_bf16(v0);
        *(unsigned*)((unsigned short*)out + o2) = ov;
    } else {
        float2 o; o.x = v0; o.y = v1;
        *(float2*)((float*)out + o2) = o;
    }
}

// ---------------------------------------------------------------------------
extern "C" void kernel_launch(void* const* d_in, const int* in_sizes, int n_in,
                              void* d_out, int out_size, void* d_ws, size_t ws_size,
                              hipStream_t stream) {
    const float* x     = (const float*)d_in[0];
    const int*   ei    = (const int*)d_in[1];
    const float* W     = (const float*)d_in[2];
    const float* a_src = (const float*)d_in[3];
    const float* a_dst = (const float*)d_in[4];
    const float* bias  = (const float*)d_in[5];
    float* outp = (float*)d_out;

    const int* e_src = ei;
    const int* e_dst = ei + NE;

    // workspace layout (bytes)
    char* base = (char*)d_ws;
    unsigned short* hb  = (unsigned short*)(base);             // NN*D bf16 (12.8MB)
    unsigned short* x1b = (unsigned short*)(base + 12800000);  // NN*D bf16 (12.8MB)
    float* al_s    = (float*)(base + 25600000);                // NN*NH
    float* al_d    = (float*)(base + 26400000);                // NN*NH
    int*   row_ptr = (int*)  (base + 27200000);                // NN+1
    unsigned short* srcs = (unsigned short*)(base + 27400064); // NE ushort (1.6MB)
    unsigned* bukbuf = (unsigned*)(base + 29000064);           // NE uint (3.2MB)
    int*   btot    = (int*)  (base + 32200064);                // NBUK
    int*   bbase   = (int*)  (base + 32201088);                // NBUK
    int*   bwp     = (int*)  (base + 32202112);                // NBUK
    unsigned short* Wpk = (unsigned short*)(base + 32203136);  // 2*2048*8 bf16 (64KB)

    // ---- W repack (also zeroes btot) + CSR build ----
    repack_kernel<<<16, 256, 0, stream>>>(W, Wpk, btot);
    const int pblocks = (NE + 2047) / 2048;   // 391
    bucket_hist_kernel<<<pblocks, 256, 0, stream>>>(e_dst, btot);
    bucket_scan_kernel<<<1, 256, 0, stream>>>(btot, bbase, bwp, row_ptr);
    partition_kernel<<<pblocks, 256, 0, stream>>>(e_src, e_dst, bwp, bukbuf);
    bucket_sort_kernel<<<NBUK, 256, 0, stream>>>(bukbuf, btot, bbase, row_ptr, srcs);

    const int gemm_blocks   = (NN + 63) / 64;
    const int gather_blocks = (NN + 3) / 4;

    // ---- layer 0 ----
    gemm_alpha_kernel<0><<<gemm_blocks, 256, 0, stream>>>(x, Wpk, a_src, a_dst,
                                                          hb, al_s, al_d);
    gather_kernel<0, 1, 1><<<gather_blocks, 256, 0, stream>>>(
        hb, al_s, al_d, row_ptr, srcs, x, bias, x1b);
    // ---- layer 1 ----
    gemm_alpha_kernel<1><<<gemm_blocks, 256, 0, stream>>>(x1b, Wpk + 2048 * 8,
                                                          a_src + D, a_dst + D,
                                                          hb, al_s, al_d);
    gather_kernel<1, 0, 0><<<gather_blocks, 256, 0, stream>>>(
        hb, al_s, al_d, row_ptr, srcs, x1b, bias + D, outp);
}

// Round 9
// 140.979 us; speedup vs baseline: 3.0906x; 1.1033x over previous
//
#include <hip/hip_runtime.h>
#include <math.h>

// GAT 2-layer forward. N=50000 nodes, E=800000 edges, D=128, H=4 heads, F=32.
constexpr int NN = 50000;
constexpr int NE = 800000;
constexpr int D  = 128;
constexpr int NH = 4;
constexpr int NBUK = (NN + 255) / 256;   // 196 dst-range buckets of 256 nodes
constexpr int CAP  = 4608;               // bucket region stride (mean 4082 + 8σ)

typedef __attribute__((ext_vector_type(8))) short short8v;  // 8 bf16 (4 VGPR)
typedef __attribute__((ext_vector_type(4))) float f32x4;    // MFMA accumulator

__device__ inline unsigned short rne_bf16(float f) {
    unsigned bits = __float_as_uint(f);
    return (unsigned short)((bits + 0x7FFFu + ((bits >> 16) & 1u)) >> 16);
}

// ============== CSR build: fixed-stride bucket sort (no hist/scan) ==========
// Partition edges into 196 dst-range buckets at fixed stride CAP; per-block
// LDS counting + one global atomic per (block,bucket) keeps writes grouped.
__global__ __launch_bounds__(256) void partition_kernel(
    const int* __restrict__ src, const int* __restrict__ dst,
    int* __restrict__ bwp, unsigned* __restrict__ bukbuf)
{
    __shared__ int cnt[NBUK];
    __shared__ int run[NBUK];
    for (int i = threadIdx.x; i < NBUK; i += 256) cnt[i] = 0;
    __syncthreads();
    const int base = blockIdx.x * 2048;
    int s_[8], b_[8], dl_[8];
    #pragma unroll
    for (int i = 0; i < 8; ++i) {
        int e = base + i * 256 + threadIdx.x;
        bool ok = (e < NE);
        s_[i] = ok ? src[e] : 0;
        int d = ok ? dst[e] : 0;
        b_[i] = d >> 8; dl_[i] = d & 255;
        if (ok) atomicAdd(&cnt[b_[i]], 1);
    }
    __syncthreads();
    for (int i = threadIdx.x; i < NBUK; i += 256)
        run[i] = cnt[i] ? atomicAdd(&bwp[i], cnt[i]) : 0;
    __syncthreads();
    #pragma unroll
    for (int i = 0; i < 8; ++i) {
        int e = base + i * 256 + threadIdx.x;
        if (e < NE) {
            int pos = atomicAdd(&run[b_[i]], 1);
            if (pos < CAP)
                bukbuf[b_[i] * CAP + pos] = (unsigned)s_[i] | ((unsigned)dl_[i] << 16);
        }
    }
}

// Per-bucket LDS counting sort -> row_start/row_end + coalesced ushort srcs.
__global__ __launch_bounds__(256) void bucket_sort_kernel(
    const unsigned* __restrict__ bukbuf, const int* __restrict__ bwp,
    int* __restrict__ row_start, int* __restrict__ row_end,
    unsigned short* __restrict__ srcs)
{
    const int b = blockIdx.x;
    const int t = threadIdx.x;
    const int cnt = min(bwp[b], CAP);
    const int base = b * CAP;
    __shared__ int hist[256];
    __shared__ int run[256];
    __shared__ int s[256];
    __shared__ unsigned short stage[CAP];
    hist[t] = 0;
    __syncthreads();
    for (int i = t; i < cnt; i += 256)
        atomicAdd(&hist[bukbuf[base + i] >> 16], 1);
    __syncthreads();
    int v = hist[t];
    s[t] = v;
    __syncthreads();
    for (int off = 1; off < 256; off <<= 1) {
        int u = (t >= off) ? s[t - off] : 0;
        __syncthreads();
        s[t] += u;
        __syncthreads();
    }
    const int excl = s[t] - v;
    const int node = b * 256 + t;
    if (node < NN) {
        row_start[node] = base + excl;
        row_end[node]   = base + excl + v;
    }
    run[t] = excl;
    __syncthreads();
    for (int i = t; i < cnt; i += 256) {
        unsigned p = bukbuf[base + i];
        int pos = atomicAdd(&run[p >> 16], 1);
        stage[pos] = (unsigned short)(p & 0xFFFFu);
    }
    __syncthreads();
    for (int i = t; i < cnt; i += 256) srcs[base + i] = stage[i];
}

// ------- W repack (per-MFMA-fragment bf16 layout) + bwp zeroing -------------
// Block 0 zeroes bwp (precedes partition in stream order; replaces the
// hipMemsetAsync whose fillBuffer dispatch was pure overhead).
__global__ __launch_bounds__(256) void repack_kernel(const float* __restrict__ W,
                                                     unsigned short* __restrict__ Wpk,
                                                     int* __restrict__ bwp) {
    if (blockIdx.x == 0 && threadIdx.x < NBUK) bwp[threadIdx.x] = 0;
    int tid = blockIdx.x * 256 + threadIdx.x;   // 2 layers * 2048 frags
    if (tid >= 2 * 2048) return;
    int layer = tid >> 11;
    int rest  = tid & 2047;
    int tile  = rest >> 8;
    int kstep = (rest >> 6) & 3;
    int lane  = rest & 63;
    int col   = tile * 16 + (lane & 15);
    int kbase = kstep * 32 + (lane >> 4) * 8;
    const float* Wl = W + (size_t)layer * D * D;
    unsigned short v[8];
    #pragma unroll
    for (int j = 0; j < 8; ++j) v[j] = rne_bf16(Wl[(kbase + j) * D + col]);
    *(uint4*)(Wpk + (size_t)tid * 8) = *(const uint4*)v;
}

// ---------------- h = x @ W via MFMA; alphas from f32 accumulator ----------
template<int BF16IN>
__global__ __launch_bounds__(256) void gemm_alpha_kernel(
    const void* __restrict__ xin, const unsigned short* __restrict__ Wpk,
    const float* __restrict__ a_src, const float* __restrict__ a_dst,
    unsigned short* __restrict__ hb, float* __restrict__ alpha_s,
    float* __restrict__ alpha_d)
{
    __shared__ unsigned short xl[64 * 128];   // 16 KB, bf16, XOR-swizzled rows
    const int t = threadIdx.x;
    const int row0 = blockIdx.x * 64;

    if constexpr (BF16IN) {
        const unsigned short* xb = (const unsigned short*)xin;
        #pragma unroll
        for (int it = 0; it < 4; ++it) {
            int idx = it * 256 + t;
            int r   = idx >> 4;
            int c8  = (idx & 15) * 8;
            int n   = row0 + r;
            uint4 v = {0u, 0u, 0u, 0u};
            if (n < NN) v = *(const uint4*)(xb + (size_t)n * D + c8);
            *(uint4*)(xl + r * 128 + (c8 ^ ((r & 7) << 3))) = v;
        }
    } else {
        const float* xf = (const float*)xin;
        #pragma unroll
        for (int it = 0; it < 8; ++it) {
            int idx = it * 256 + t;
            int r   = idx >> 5;
            int c4  = (idx & 31) * 4;
            int n   = row0 + r;
            float4 v;
            if (n < NN) v = *(const float4*)(xf + (size_t)n * D + c4);
            else { v.x = 0.f; v.y = 0.f; v.z = 0.f; v.w = 0.f; }
            unsigned p0 = ((unsigned)rne_bf16(v.y) << 16) | rne_bf16(v.x);
            unsigned p1 = ((unsigned)rne_bf16(v.w) << 16) | rne_bf16(v.z);
            uint2 pv; pv.x = p0; pv.y = p1;
            *(uint2*)(xl + r * 128 + (c4 ^ ((r & 7) << 3))) = pv;
        }
    }
    __syncthreads();

    const int wv  = t >> 6;
    const int l   = t & 63;
    const int l15 = l & 15;
    const int g   = l >> 4;
    const int strip = wv * 16;
    const int arow  = strip + l15;

    f32x4 acc[8];
    #pragma unroll
    for (int i = 0; i < 8; ++i) acc[i] = (f32x4){0.f, 0.f, 0.f, 0.f};

    #pragma unroll
    for (int ks = 0; ks < 4; ++ks) {
        const int k0 = ks * 32 + g * 8;
        short8v a = *(const short8v*)(xl + arow * 128 + (k0 ^ ((arow & 7) << 3)));
        #pragma unroll
        for (int tl = 0; tl < 8; ++tl) {
            short8v b = *(const short8v*)(Wpk + ((size_t)(tl * 4 + ks) * 64 + l) * 8);
            acc[tl] = __builtin_amdgcn_mfma_f32_16x16x32_bf16(a, b, acc[tl], 0, 0, 0);
        }
    }

    float as_t[8], ad_t[8];
    #pragma unroll
    for (int tl = 0; tl < 8; ++tl) {
        as_t[tl] = a_src[tl * 16 + l15];
        ad_t[tl] = a_dst[tl * 16 + l15];
    }

    #pragma unroll
    for (int r = 0; r < 4; ++r) {
        const int n = row0 + strip + g * 4 + r;
        if (n < NN) {
            #pragma unroll
            for (int tl = 0; tl < 8; ++tl)
                hb[(size_t)n * D + tl * 16 + l15] = rne_bf16(acc[tl][r]);
        }
        #pragma unroll
        for (int hd = 0; hd < NH; ++hd) {
            float ps = acc[2*hd][r] * as_t[2*hd] + acc[2*hd+1][r] * as_t[2*hd+1];
            float pd = acc[2*hd][r] * ad_t[2*hd] + acc[2*hd+1][r] * ad_t[2*hd+1];
            #pragma unroll
            for (int off = 1; off < 16; off <<= 1) {
                ps += __shfl_xor(ps, off);
                pd += __shfl_xor(pd, off);
            }
            if (l15 == 0 && n < NN) {
                alpha_s[n * NH + hd] = ps;
                alpha_d[n * NH + hd] = pd;
            }
        }
    }
}

// ---------------- per-dst-node gather + softmax + aggregate + epilogue ------
// QUARTER-WAVE per node (4 nodes/wave, 16 nodes/block). Lane owns 8 cols of
// its node; den and acc are complete within the quarter -> NO cross-lane
// reduce. Weight phase (leaky+exp x4) runs on all 64 lanes (one 16-edge chunk
// per quarter). Per edge: 3 bpermute broadcasts within the quarter.
template<int IN_BF16, int OUT_BF16, int ACT>
__global__ __launch_bounds__(256) void gather_kernel(
    const unsigned short* __restrict__ hb, const float* __restrict__ alpha_s,
    const float* __restrict__ alpha_d, const int* __restrict__ row_start,
    const int* __restrict__ row_end, const unsigned short* __restrict__ srcs,
    const void* __restrict__ x_in, const float* __restrict__ bias,
    void* __restrict__ out)
{
    const int lane = threadIdx.x & 63;
    const int q    = lane >> 4;          // quarter index (node slot)
    const int ql   = lane & 15;          // col group: cols [8*ql, 8*ql+8)
    const int head = ql >> 2;            // all 8 cols share one head
    const int lb   = q * 16;             // quarter's lane base
    const int n = blockIdx.x * 16 + (threadIdx.x >> 6) * 4 + q;
    if (n >= NN) return;

    const int start = row_start[n];
    const int end   = row_end[n];
    const float4 ad4 = *(const float4*)&alpha_d[n * NH];

    float acc[8];
    #pragma unroll
    for (int c = 0; c < 8; ++c) acc[c] = 0.f;
    float den = 0.f;

    for (int base = start; base < end; base += 16) {
        const int cnt = min(16, end - base);
        int msrc = 0;
        unsigned uw01 = 0, uw23 = 0;
        if (ql < cnt) {
            msrc = srcs[base + ql];
            const float4 as4 = *(const float4*)&alpha_s[msrc * NH];
            float e0 = as4.x + ad4.x; e0 = (e0 > 0.f) ? e0 : 0.2f * e0;
            float e1 = as4.y + ad4.y; e1 = (e1 > 0.f) ? e1 : 0.2f * e1;
            float e2 = as4.z + ad4.z; e2 = (e2 > 0.f) ? e2 : 0.2f * e2;
            float e3 = as4.w + ad4.w; e3 = (e3 > 0.f) ? e3 : 0.2f * e3;
            float w0 = __expf(e0), w1 = __expf(e1);
            float w2 = __expf(e2), w3 = __expf(e3);
            uw01 = ((unsigned)rne_bf16(w1) << 16) | rne_bf16(w0);
            uw23 = ((unsigned)rne_bf16(w3) << 16) | rne_bf16(w2);
        }
        for (int m = 0; m < cnt; ++m) {
            int s = __shfl(msrc, lb + m);
            unsigned b01 = (unsigned)__shfl((int)uw01, lb + m);
            unsigned b23 = (unsigned)__shfl((int)uw23, lb + m);
            unsigned uw = (head < 2) ? b01 : b23;
            float w = __uint_as_float((head & 1) ? (uw & 0xFFFF0000u) : (uw << 16));
            den += w;
            const uint4 hv = *(const uint4*)(hb + ((size_t)s << 7) + (ql << 3));
            acc[0] = fmaf(w, __uint_as_float(hv.x << 16),          acc[0]);
            acc[1] = fmaf(w, __uint_as_float(hv.x & 0xFFFF0000u),  acc[1]);
            acc[2] = fmaf(w, __uint_as_float(hv.y << 16),          acc[2]);
            acc[3] = fmaf(w, __uint_as_float(hv.y & 0xFFFF0000u),  acc[3]);
            acc[4] = fmaf(w, __uint_as_float(hv.z << 16),          acc[4]);
            acc[5] = fmaf(w, __uint_as_float(hv.z & 0xFFFF0000u),  acc[5]);
            acc[6] = fmaf(w, __uint_as_float(hv.w << 16),          acc[6]);
            acc[7] = fmaf(w, __uint_as_float(hv.w & 0xFFFF0000u),  acc[7]);
        }
    }

    // epilogue: lane owns cols [8*ql, 8*ql+8) of node n — no reduce needed
    const float inv = 1.f / (den + 1e-16f);
    const size_t o8 = (size_t)n * D + ql * 8;
    float xi[8];
    if constexpr (IN_BF16) {
        const uint4 xv = *(const uint4*)((const unsigned short*)x_in + o8);
        xi[0] = __uint_as_float(xv.x << 16);
        xi[1] = __uint_as_float(xv.x & 0xFFFF0000u);
        xi[2] = __uint_as_float(xv.y << 16);
        xi[3] = __uint_as_float(xv.y & 0xFFFF0000u);
        xi[4] = __uint_as_float(xv.z << 16);
        xi[5] = __uint_as_float(xv.z & 0xFFFF0000u);
        xi[6] = __uint_as_float(xv.w << 16);
        xi[7] = __uint_as_float(xv.w & 0xFFFF0000u);
    } else {
        const float4 a = *(const float4*)((const float*)x_in + o8);
        const float4 b = *(const float4*)((const float*)x_in + o8 + 4);
        xi[0]=a.x; xi[1]=a.y; xi[2]=a.z; xi[3]=a.w;
        xi[4]=b.x; xi[5]=b.y; xi[6]=b.z; xi[7]=b.w;
    }
    const float4 ba = *(const float4*)(bias + ql * 8);
    const float4 bb = *(const float4*)(bias + ql * 8 + 4);
    const float bi[8] = {ba.x, ba.y, ba.z, ba.w, bb.x, bb.y, bb.z, bb.w};
    float o[8];
    #pragma unroll
    for (int c = 0; c < 8; ++c) {
        float v = fmaf(acc[c], inv, xi[c]) + bi[c];
        if constexpr (ACT) v = (v > 0.f) ? v : (__expf(v) - 1.f);
        o[c] = v;
    }
    if constexpr (OUT_BF16) {
        unsigned short ov[8];
        #pragma unroll
        for (int c = 0; c < 8; ++c) ov[c] = rne_bf16(o[c]);
        *(uint4*)((unsigned short*)out + o8) = *(const uint4*)ov;
    } else {
        float4 oa = {o[0], o[1], o[2], o[3]};
        float4 ob = {o[4], o[5], o[6], o[7]};
        *(float4*)((float*)out + o8)     = oa;
        *(float4*)((float*)out + o8 + 4) = ob;
    }
}

// ---------------------------------------------------------------------------
extern "C" void kernel_launch(void* const* d_in, const int* in_sizes, int n_in,
                              void* d_out, int out_size, void* d_ws, size_t ws_size,
                              hipStream_t stream) {
    const float* x     = (const float*)d_in[0];
    const int*   ei    = (const int*)d_in[1];
    const float* W     = (const float*)d_in[2];
    const float* a_src = (const float*)d_in[3];
    const float* a_dst = (const float*)d_in[4];
    const float* bias  = (const float*)d_in[5];
    float* outp = (float*)d_out;

    const int* e_src = ei;
    const int* e_dst = ei + NE;

    // workspace layout (bytes)
    char* base = (char*)d_ws;
    unsigned short* hb  = (unsigned short*)(base);             // NN*D bf16 (12.8MB)
    unsigned short* x1b = (unsigned short*)(base + 12800000);  // NN*D bf16 (12.8MB)
    float* al_s      = (float*)(base + 25600000);              // NN*NH
    float* al_d      = (float*)(base + 26400000);              // NN*NH
    int*   row_start = (int*)  (base + 27200000);              // NN
    int*   row_end   = (int*)  (base + 27400000);              // NN
    unsigned short* srcs = (unsigned short*)(base + 27600000); // NBUK*CAP (1.81MB)
    unsigned* bukbuf = (unsigned*)(base + 29406336);           // NBUK*CAP (3.61MB)
    int*   bwp       = (int*)  (base + 33019008);              // NBUK
    unsigned short* Wpk = (unsigned short*)(base + 33019792);  // 2*2048*8 bf16 (64KB)

    // ---- W repack (also zeroes bwp) + bucket CSR build ----
    repack_kernel<<<16, 256, 0, stream>>>(W, Wpk, bwp);
    const int pblocks = (NE + 2047) / 2048;   // 391
    partition_kernel<<<pblocks, 256, 0, stream>>>(e_src, e_dst, bwp, bukbuf);
    bucket_sort_kernel<<<NBUK, 256, 0, stream>>>(bukbuf, bwp, row_start, row_end, srcs);

    const int gemm_blocks   = (NN + 63) / 64;
    const int gather_blocks = (NN + 15) / 16;

    // ---- layer 0 ----
    gemm_alpha_kernel<0><<<gemm_blocks, 256, 0, stream>>>(x, Wpk, a_src, a_dst,
                                                          hb, al_s, al_d);
    gather_kernel<0, 1, 1><<<gather_blocks, 256, 0, stream>>>(
        hb, al_s, al_d, row_start, row_end, srcs, x, bias, x1b);
    // ---- layer 1 ----
    gemm_alpha_kernel<1><<<gemm_blocks, 256, 0, stream>>>(x1b, Wpk + 2048 * 8,
                                                          a_src + D, a_dst + D,
                                                          hb, al_s, al_d);
    gather_kernel<1, 0, 0><<<gather_blocks, 256, 0, stream>>>(
        hb, al_s, al_d, row_start, row_end, srcs, x1b, bias + D, outp);
}

// Round 10
// 133.509 us; speedup vs baseline: 3.2635x; 1.0560x over previous
//
#include <hip/hip_runtime.h>
#include <math.h>

// GAT 2-layer forward. N=50000 nodes, E=800000 edges, D=128, H=4 heads, F=32.
constexpr int NN = 50000;
constexpr int NE = 800000;
constexpr int D  = 128;
constexpr int NH = 4;
constexpr int NBUK = (NN + 255) / 256;   // 196 dst-range buckets of 256 nodes
constexpr int CAP  = 4608;               // bucket region stride (mean 4082 + 8σ)
constexpr int FR_PER_LAYER = 9 * 4 * 64; // 9 B-tiles (8 W + 1 alpha-C) per layer

typedef __attribute__((ext_vector_type(8))) short short8v;  // 8 bf16 (4 VGPR)
typedef __attribute__((ext_vector_type(4))) float f32x4;    // MFMA accumulator

__device__ inline unsigned short rne_bf16(float f) {
    unsigned bits = __float_as_uint(f);
    return (unsigned short)((bits + 0x7FFFu + ((bits >> 16) & 1u)) >> 16);
}

// acc += a.bf16[0]*b.bf16[0] + a.bf16[1]*b.bf16[1]  (f32 accumulate)
#define DOT2BF(accv, pa, pb) \
    asm("v_dot2_f32_bf16 %0, %1, %2, %0" : "+v"(accv) : "v"(pa), "v"(pb))

// ============== CSR build: fixed-stride bucket sort (no hist/scan) ==========
__global__ __launch_bounds__(256) void partition_kernel(
    const int* __restrict__ src, const int* __restrict__ dst,
    int* __restrict__ bwp, unsigned* __restrict__ bukbuf)
{
    __shared__ int cnt[NBUK];
    __shared__ int run[NBUK];
    for (int i = threadIdx.x; i < NBUK; i += 256) cnt[i] = 0;
    __syncthreads();
    const int base = blockIdx.x * 2048;
    int s_[8], b_[8], dl_[8];
    #pragma unroll
    for (int i = 0; i < 8; ++i) {
        int e = base + i * 256 + threadIdx.x;
        bool ok = (e < NE);
        s_[i] = ok ? src[e] : 0;
        int d = ok ? dst[e] : 0;
        b_[i] = d >> 8; dl_[i] = d & 255;
        if (ok) atomicAdd(&cnt[b_[i]], 1);
    }
    __syncthreads();
    for (int i = threadIdx.x; i < NBUK; i += 256)
        run[i] = cnt[i] ? atomicAdd(&bwp[i], cnt[i]) : 0;
    __syncthreads();
    #pragma unroll
    for (int i = 0; i < 8; ++i) {
        int e = base + i * 256 + threadIdx.x;
        if (e < NE) {
            int pos = atomicAdd(&run[b_[i]], 1);
            if (pos < CAP)
                bukbuf[b_[i] * CAP + pos] = (unsigned)s_[i] | ((unsigned)dl_[i] << 16);
        }
    }
}

// Per-bucket LDS counting sort -> row_start/row_end + coalesced ushort srcs.
__global__ __launch_bounds__(256) void bucket_sort_kernel(
    const unsigned* __restrict__ bukbuf, const int* __restrict__ bwp,
    int* __restrict__ row_start, int* __restrict__ row_end,
    unsigned short* __restrict__ srcs)
{
    const int b = blockIdx.x;
    const int t = threadIdx.x;
    const int cnt = min(bwp[b], CAP);
    const int base = b * CAP;
    __shared__ int hist[256];
    __shared__ int run[256];
    __shared__ int s[256];
    __shared__ unsigned short stage[CAP];
    hist[t] = 0;
    __syncthreads();
    for (int i = t; i < cnt; i += 256)
        atomicAdd(&hist[bukbuf[base + i] >> 16], 1);
    __syncthreads();
    int v = hist[t];
    s[t] = v;
    __syncthreads();
    for (int off = 1; off < 256; off <<= 1) {
        int u = (t >= off) ? s[t - off] : 0;
        __syncthreads();
        s[t] += u;
        __syncthreads();
    }
    const int excl = s[t] - v;
    const int node = b * 256 + t;
    if (node < NN) {
        row_start[node] = base + excl;
        row_end[node]   = base + excl + v;
    }
    run[t] = excl;
    __syncthreads();
    for (int i = t; i < cnt; i += 256) {
        unsigned p = bukbuf[base + i];
        int pos = atomicAdd(&run[p >> 16], 1);
        stage[pos] = (unsigned short)(p & 0xFFFFu);
    }
    __syncthreads();
    for (int i = t; i < cnt; i += 256) srcs[base + i] = stage[i];
}

// ------- W repack + alpha-C tile + bwp zeroing ------------------------------
// Wpk layout: [layer][tile(9)][kstep(4)][lane(64)][j(8)] bf16. Tiles 0..7 are
// W columns; tile 8 is C = [W.a_src (cols 0..3) | W.a_dst (cols 4..7)], so the
// MFMA loop computes alphas directly (alpha = h.a = x@(W.a)).
__global__ __launch_bounds__(256) void repack_kernel(
    const float* __restrict__ W, const float* __restrict__ a_src,
    const float* __restrict__ a_dst, unsigned short* __restrict__ Wpk,
    int* __restrict__ bwp)
{
    if (blockIdx.x == 0 && threadIdx.x < NBUK) bwp[threadIdx.x] = 0;
    int tid = blockIdx.x * 256 + threadIdx.x;
    if (tid >= 2 * FR_PER_LAYER) return;
    int layer = tid / FR_PER_LAYER;
    int rest  = tid % FR_PER_LAYER;
    int tile  = rest >> 8;            // 0..8
    int kstep = (rest >> 6) & 3;
    int lane  = rest & 63;
    int col   = lane & 15;
    int kbase = kstep * 32 + (lane >> 4) * 8;
    const float* Wl = W + (size_t)layer * D * D;
    unsigned short v[8];
    if (tile < 8) {
        int c = tile * 16 + col;
        #pragma unroll
        for (int j = 0; j < 8; ++j) v[j] = rne_bf16(Wl[(kbase + j) * D + c]);
    } else {
        #pragma unroll
        for (int j = 0; j < 8; ++j) v[j] = 0;
        if (col < 8) {
            const float* av = ((col < 4) ? a_src : a_dst) + layer * D + (col & 3) * 32;
            const int hbase = (col & 3) * 32;
            for (int j = 0; j < 8; ++j) {
                float sum = 0.f;
                const float* wr = Wl + (size_t)(kbase + j) * D + hbase;
                #pragma unroll
                for (int jj = 0; jj < 32; ++jj) sum = fmaf(wr[jj], av[jj], sum);
                v[j] = rne_bf16(sum);
            }
        }
    }
    *(uint4*)(Wpk + (size_t)tid * 8) = *(const uint4*)v;
}

// ---------------- h = x @ W via MFMA; alphas via the C tile ----------------
template<int BF16IN>
__global__ __launch_bounds__(256) void gemm_alpha_kernel(
    const void* __restrict__ xin, const unsigned short* __restrict__ Wpk,
    unsigned short* __restrict__ hb, float* __restrict__ alpha_s,
    float* __restrict__ alpha_d)
{
    __shared__ unsigned short xl[64 * 128];   // 16 KB, bf16, XOR-swizzled rows
    const int t = threadIdx.x;
    const int row0 = blockIdx.x * 64;

    if constexpr (BF16IN) {
        const unsigned short* xb = (const unsigned short*)xin;
        #pragma unroll
        for (int it = 0; it < 4; ++it) {
            int idx = it * 256 + t;
            int r   = idx >> 4;
            int c8  = (idx & 15) * 8;
            int n   = row0 + r;
            uint4 v = {0u, 0u, 0u, 0u};
            if (n < NN) v = *(const uint4*)(xb + (size_t)n * D + c8);
            *(uint4*)(xl + r * 128 + (c8 ^ ((r & 7) << 3))) = v;
        }
    } else {
        const float* xf = (const float*)xin;
        #pragma unroll
        for (int it = 0; it < 8; ++it) {
            int idx = it * 256 + t;
            int r   = idx >> 5;
            int c4  = (idx & 31) * 4;
            int n   = row0 + r;
            float4 v;
            if (n < NN) v = *(const float4*)(xf + (size_t)n * D + c4);
            else { v.x = 0.f; v.y = 0.f; v.z = 0.f; v.w = 0.f; }
            unsigned p0 = ((unsigned)rne_bf16(v.y) << 16) | rne_bf16(v.x);
            unsigned p1 = ((unsigned)rne_bf16(v.w) << 16) | rne_bf16(v.z);
            uint2 pv; pv.x = p0; pv.y = p1;
            *(uint2*)(xl + r * 128 + (c4 ^ ((r & 7) << 3))) = pv;
        }
    }
    __syncthreads();

    const int wv  = t >> 6;
    const int l   = t & 63;
    const int l15 = l & 15;
    const int g   = l >> 4;
    const int strip = wv * 16;
    const int arow  = strip + l15;

    f32x4 acc[9];
    #pragma unroll
    for (int i = 0; i < 9; ++i) acc[i] = (f32x4){0.f, 0.f, 0.f, 0.f};

    #pragma unroll
    for (int ks = 0; ks < 4; ++ks) {
        const int k0 = ks * 32 + g * 8;
        short8v a = *(const short8v*)(xl + arow * 128 + (k0 ^ ((arow & 7) << 3)));
        #pragma unroll
        for (int tl = 0; tl < 9; ++tl) {
            short8v b = *(const short8v*)(Wpk + ((size_t)(tl * 4 + ks) * 64 + l) * 8);
            acc[tl] = __builtin_amdgcn_mfma_f32_16x16x32_bf16(a, b, acc[tl], 0, 0, 0);
        }
    }

    // D layout: row = g*4 + r (within strip), col = l15
    #pragma unroll
    for (int r = 0; r < 4; ++r) {
        const int n = row0 + strip + g * 4 + r;
        if (n < NN) {
            #pragma unroll
            for (int tl = 0; tl < 8; ++tl)
                hb[(size_t)n * D + tl * 16 + l15] = rne_bf16(acc[tl][r]);
            const float av = acc[8][r];
            if (l15 < 4)      alpha_s[n * NH + l15]       = av;
            else if (l15 < 8) alpha_d[n * NH + (l15 - 4)] = av;
        }
    }
}

// ---------------- per-dst-node gather + softmax + aggregate + epilogue ------
// Quarter-wave per node; lane owns 8 cols. Inner loop processes 2 EDGES per
// iteration via v_perm_b32 pairing + v_dot2_f32_bf16 (2 MACs/inst, f32 acc,
// no unpack). Denominator rides a dot2 against (1.0,1.0) bf16.
template<int IN_BF16, int OUT_BF16, int ACT>
__global__ __launch_bounds__(256) void gather_kernel(
    const unsigned short* __restrict__ hb, const float* __restrict__ alpha_s,
    const float* __restrict__ alpha_d, const int* __restrict__ row_start,
    const int* __restrict__ row_end, const unsigned short* __restrict__ srcs,
    const void* __restrict__ x_in, const float* __restrict__ bias,
    void* __restrict__ out)
{
    const int lane = threadIdx.x & 63;
    const int q    = lane >> 4;          // quarter index (node slot)
    const int ql   = lane & 15;          // col group: cols [8*ql, 8*ql+8)
    const int head = ql >> 2;            // all 8 cols share one head
    const int lb   = q * 16;             // quarter's lane base
    const int n = blockIdx.x * 16 + (threadIdx.x >> 6) * 4 + q;
    if (n >= NN) return;

    const int start = row_start[n];
    const int end   = row_end[n];
    const float4 ad4 = *(const float4*)&alpha_d[n * NH];
    // perm selector for my head's half: lo-half (h even) or hi-half (h odd)
    const unsigned wsel = (head & 1) ? 0x07060302u : 0x05040100u;
    const unsigned ones = 0x3F803F80u;   // (1.0, 1.0) bf16 pair

    float acc[8];
    #pragma unroll
    for (int c = 0; c < 8; ++c) acc[c] = 0.f;
    float den = 0.f;

    for (int base = start; base < end; base += 16) {
        const int cnt = min(16, end - base);
        int msrc = 0;
        unsigned uw01 = 0, uw23 = 0;
        if (ql < cnt) {
            msrc = srcs[base + ql];
            const float4 as4 = *(const float4*)&alpha_s[msrc * NH];
            float e0 = as4.x + ad4.x; e0 = (e0 > 0.f) ? e0 : 0.2f * e0;
            float e1 = as4.y + ad4.y; e1 = (e1 > 0.f) ? e1 : 0.2f * e1;
            float e2 = as4.z + ad4.z; e2 = (e2 > 0.f) ? e2 : 0.2f * e2;
            float e3 = as4.w + ad4.w; e3 = (e3 > 0.f) ? e3 : 0.2f * e3;
            float w0 = __expf(e0), w1 = __expf(e1);
            float w2 = __expf(e2), w3 = __expf(e3);
            uw01 = ((unsigned)rne_bf16(w1) << 16) | rne_bf16(w0);
            uw23 = ((unsigned)rne_bf16(w3) << 16) | rne_bf16(w2);
        }
        const int mm = (cnt + 1) & ~1;   // phantom odd edge has w=0, src=0
        for (int m = 0; m < mm; m += 2) {
            int s0 = __shfl(msrc, lb + m);
            int s1 = __shfl(msrc, lb + m + 1);
            unsigned a01 = (unsigned)__shfl((int)uw01, lb + m);
            unsigned a23 = (unsigned)__shfl((int)uw23, lb + m);
            unsigned c01 = (unsigned)__shfl((int)uw01, lb + m + 1);
            unsigned c23 = (unsigned)__shfl((int)uw23, lb + m + 1);
            unsigned uwA = (head < 2) ? a01 : a23;   // edge m,   heads pair
            unsigned uwB = (head < 2) ? c01 : c23;   // edge m+1, heads pair
            // wpair = (w_e0[head] lo16, w_e1[head] hi16)
            unsigned wpair = __builtin_amdgcn_perm(uwB, uwA, wsel);
            DOT2BF(den, wpair, ones);
            const uint4 h0 = *(const uint4*)(hb + ((size_t)s0 << 7) + (ql << 3));
            const uint4 h1 = *(const uint4*)(hb + ((size_t)s1 << 7) + (ql << 3));
            unsigned p;
            p = __builtin_amdgcn_perm(h1.x, h0.x, 0x05040100u); DOT2BF(acc[0], p, wpair);
            p = __builtin_amdgcn_perm(h1.x, h0.x, 0x07060302u); DOT2BF(acc[1], p, wpair);
            p = __builtin_amdgcn_perm(h1.y, h0.y, 0x05040100u); DOT2BF(acc[2], p, wpair);
            p = __builtin_amdgcn_perm(h1.y, h0.y, 0x07060302u); DOT2BF(acc[3], p, wpair);
            p = __builtin_amdgcn_perm(h1.z, h0.z, 0x05040100u); DOT2BF(acc[4], p, wpair);
            p = __builtin_amdgcn_perm(h1.z, h0.z, 0x07060302u); DOT2BF(acc[5], p, wpair);
            p = __builtin_amdgcn_perm(h1.w, h0.w, 0x05040100u); DOT2BF(acc[6], p, wpair);
            p = __builtin_amdgcn_perm(h1.w, h0.w, 0x07060302u); DOT2BF(acc[7], p, wpair);
        }
    }

    // epilogue: lane owns cols [8*ql, 8*ql+8) of node n — no reduce needed
    const float inv = 1.f / (den + 1e-16f);
    const size_t o8 = (size_t)n * D + ql * 8;
    float xi[8];
    if constexpr (IN_BF16) {
        const uint4 xv = *(const uint4*)((const unsigned short*)x_in + o8);
        xi[0] = __uint_as_float(xv.x << 16);
        xi[1] = __uint_as_float(xv.x & 0xFFFF0000u);
        xi[2] = __uint_as_float(xv.y << 16);
        xi[3] = __uint_as_float(xv.y & 0xFFFF0000u);
        xi[4] = __uint_as_float(xv.z << 16);
        xi[5] = __uint_as_float(xv.z & 0xFFFF0000u);
        xi[6] = __uint_as_float(xv.w << 16);
        xi[7] = __uint_as_float(xv.w & 0xFFFF0000u);
    } else {
        const float4 a = *(const float4*)((const float*)x_in + o8);
        const float4 b = *(const float4*)((const float*)x_in + o8 + 4);
        xi[0]=a.x; xi[1]=a.y; xi[2]=a.z; xi[3]=a.w;
        xi[4]=b.x; xi[5]=b.y; xi[6]=b.z; xi[7]=b.w;
    }
    const float4 ba = *(const float4*)(bias + ql * 8);
    const float4 bb = *(const float4*)(bias + ql * 8 + 4);
    const float bi[8] = {ba.x, ba.y, ba.z, ba.w, bb.x, bb.y, bb.z, bb.w};
    float o[8];
    #pragma unroll
    for (int c = 0; c < 8; ++c) {
        float v = fmaf(acc[c], inv, xi[c]) + bi[c];
        if constexpr (ACT) v = (v > 0.f) ? v : (__expf(v) - 1.f);
        o[c] = v;
    }
    if constexpr (OUT_BF16) {
        unsigned short ov[8];
        #pragma unroll
        for (int c = 0; c < 8; ++c) ov[c] = rne_bf16(o[c]);
        *(uint4*)((unsigned short*)out + o8) = *(const uint4*)ov;
    } else {
        float4 oa = {o[0], o[1], o[2], o[3]};
        float4 ob = {o[4], o[5], o[6], o[7]};
        *(float4*)((float*)out + o8)     = oa;
        *(float4*)((float*)out + o8 + 4) = ob;
    }
}

// ---------------------------------------------------------------------------
extern "C" void kernel_launch(void* const* d_in, const int* in_sizes, int n_in,
                              void* d_out, int out_size, void* d_ws, size_t ws_size,
                              hipStream_t stream) {
    const float* x     = (const float*)d_in[0];
    const int*   ei    = (const int*)d_in[1];
    const float* W     = (const float*)d_in[2];
    const float* a_src = (const float*)d_in[3];
    const float* a_dst = (const float*)d_in[4];
    const float* bias  = (const float*)d_in[5];
    float* outp = (float*)d_out;

    const int* e_src = ei;
    const int* e_dst = ei + NE;

    // workspace layout (bytes)
    char* base = (char*)d_ws;
    unsigned short* hb  = (unsigned short*)(base);             // NN*D bf16 (12.8MB)
    unsigned short* x1b = (unsigned short*)(base + 12800000);  // NN*D bf16 (12.8MB)
    float* al_s      = (float*)(base + 25600000);              // NN*NH
    float* al_d      = (float*)(base + 26400000);              // NN*NH
    int*   row_start = (int*)  (base + 27200000);              // NN
    int*   row_end   = (int*)  (base + 27400000);              // NN
    unsigned short* srcs = (unsigned short*)(base + 27600000); // NBUK*CAP (1.81MB)
    unsigned* bukbuf = (unsigned*)(base + 29406336);           // NBUK*CAP (3.61MB)
    int*   bwp       = (int*)  (base + 33019008);              // NBUK
    unsigned short* Wpk = (unsigned short*)(base + 33019792);  // 2*2304*8 bf16 (72KB)

    // ---- W repack + alpha-C tiles (also zeroes bwp) + bucket CSR build ----
    const int rblocks = (2 * FR_PER_LAYER + 255) / 256;   // 18
    repack_kernel<<<rblocks, 256, 0, stream>>>(W, a_src, a_dst, Wpk, bwp);
    const int pblocks = (NE + 2047) / 2048;   // 391
    partition_kernel<<<pblocks, 256, 0, stream>>>(e_src, e_dst, bwp, bukbuf);
    bucket_sort_kernel<<<NBUK, 256, 0, stream>>>(bukbuf, bwp, row_start, row_end, srcs);

    const int gemm_blocks   = (NN + 63) / 64;
    const int gather_blocks = (NN + 15) / 16;

    // ---- layer 0 ----
    gemm_alpha_kernel<0><<<gemm_blocks, 256, 0, stream>>>(x, Wpk, hb, al_s, al_d);
    gather_kernel<0, 1, 1><<<gather_blocks, 256, 0, stream>>>(
        hb, al_s, al_d, row_start, row_end, srcs, x, bias, x1b);
    // ---- layer 1 ----
    gemm_alpha_kernel<1><<<gemm_blocks, 256, 0, stream>>>(
        x1b, Wpk + (size_t)FR_PER_LAYER * 8, hb, al_s, al_d);
    gather_kernel<1, 0, 0><<<gather_blocks, 256, 0, stream>>>(
        hb, al_s, al_d, row_start, row_end, srcs, x1b, bias + D, outp);
}